// Round 12
// baseline (299.719 us; speedup 1.0000x reference)
//
#include <hip/hip_runtime.h>

typedef unsigned int u32;
typedef _Float16 f16;
typedef short s16;
typedef _Float16 f16x8 __attribute__((ext_vector_type(8)));
typedef short bf16x8 __attribute__((ext_vector_type(8)));
typedef float f32x4 __attribute__((ext_vector_type(4)));

#define MFMA16(a,b,c) __builtin_amdgcn_mfma_f32_16x16x32_f16(a,b,c,0,0,0)
#define MFMABF(a,b,c) __builtin_amdgcn_mfma_f32_16x16x32_bf16(a,b,c,0,0,0)

namespace {

constexpr int VV = 90, BTV = 256*90, NB = 1024, NT = 1024;

// ---- LDS layout (2-byte-element offsets) ----
constexpr int XT  = 0;         // f16 [96][272] x1T staging
constexpr int UT  = 0;         // bf16 [128][136]; cols 128..135 = col-partial-max[wave]
constexpr int OS1 = 0;         // f16 [256][90] out1 staging (Ph10: UT/US dead)
constexpr int US  = 17408;     // bf16 [90][96]
constexpr int G1T = 26112;     // bf16 [96][136]
constexpr int THT = 39168;     // f16 [96][136]; f32 scratch for Et col partials after Ph45
constexpr int OS2 = 39168;     // f16 [256][90] out2 staging (M1/M2 dead), ends 62208
constexpr int PHT = 52224;     // f16 [96][136]
constexpr int X2  = 52224;     // f16 [96][272] x2T staging (over PHT+G2T; dead until Ph3 epilogue)
constexpr int G2T = 65280;     // bf16 [96][136]  (ends 78336)
constexpr int M1o = 39168;     // bf16 [128][96]  over THT
constexpr int M2o = 51456;     // bf16 [128][96]
constexpr int Z1o = 26112;     // bf16 [96][136]  over G1T
constexpr int Z2o = 65280;     // bf16 [96][136]  over G2T
constexpr int SBASE = 78336;   // f32 stats area
constexpr int oX1MV=0, oX2MT=256, oMRT=352, oISRT=480, oMCT=608, oISCT=736,
              oMRS=864, oISRS=960, oMCS=1056, oISCS=1152, oRED1=1248, oRED2=1376, oSCAL=1504;
// oSCAL: 0..5 fusion weights, 8=M_s
constexpr int oMSP = 1520;     // 6 per-wave E_s row-max partials
constexpr int SWORDS = 1536;
constexpr int SMEM_BYTES = SBASE*2 + SWORDS*4;   // 162816 <= 163840

// ---- ws layout (bytes) ----
constexpr size_t wThP=0, wGP=65536, wPhP=131072, wWP=196608,
  wBeTh=262144, wBeG=262656, wBePh=263168, wBwe=263680, wCsw=264704, wBwsum=265216;

__device__ __forceinline__ f16x8 frag_ld(const f16* p, int stride){
  int l = threadIdx.x & 63;
  return *(const f16x8*)(p + (l & 15) * stride + (l >> 4) * 8);
}
__device__ __forceinline__ bf16x8 bfrag_ld(const s16* p, int stride){
  int l = threadIdx.x & 63;
  return *(const bf16x8*)(p + (l & 15) * stride + (l >> 4) * 8);
}
__device__ __forceinline__ s16 f2bf(float x){
  u32 u = __float_as_uint(x);
  u += 0x7FFFu + ((u >> 16) & 1u);   // RNE
  return (s16)(u >> 16);
}
__device__ __forceinline__ float bf2f(s16 h){
  return __uint_as_float(((u32)(unsigned short)h) << 16);
}

// =================== prep kernels (unchanged, correct) ===================
__global__ void prep_weights(
    const float* __restrict__ th_w, const float* __restrict__ th_b,
    const float* __restrict__ th_bng, const float* __restrict__ th_bnb,
    const float* __restrict__ th_bnm, const float* __restrict__ th_bnv,
    const float* __restrict__ g_w, const float* __restrict__ g_b,
    const float* __restrict__ g_bng, const float* __restrict__ g_bnb,
    const float* __restrict__ g_bnm, const float* __restrict__ g_bnv,
    const float* __restrict__ ph_w, const float* __restrict__ ph_b,
    const float* __restrict__ ph_bng, const float* __restrict__ ph_bnb,
    const float* __restrict__ ph_bnm, const float* __restrict__ ph_bnv,
    const float* __restrict__ W_w, const float* __restrict__ W_b,
    const float* __restrict__ W_bng, const float* __restrict__ W_bnb,
    const float* __restrict__ W_bnm, const float* __restrict__ W_bnv,
    char* __restrict__ ws)
{
  __shared__ float red[256];
  const int b = blockIdx.x, tid = threadIdx.x;
  f16* ThP = (f16*)(ws + wThP); f16* GP = (f16*)(ws + wGP);
  f16* PhP = (f16*)(ws + wPhP); s16* WP = (s16*)(ws + wWP);
  float* beTh = (float*)(ws + wBeTh); float* beG = (float*)(ws + wBeG);
  float* bePh = (float*)(ws + wBePh); float* bwe = (float*)(ws + wBwe);
  if (b < 128){
    const int c = b, t = tid;
    {
      float s = th_bng[t] * rsqrtf(th_bnv[t] + 1e-5f);
      float d = th_bnb[t] - th_bnm[t] * s;
      float w = th_w[c*256 + t];
      ThP[c*256 + t] = (f16)(w * s);
      red[tid] = w * d; __syncthreads();
      for (int o = 128; o > 0; o >>= 1){ if (tid < o) red[tid] += red[tid+o]; __syncthreads(); }
      if (tid == 0) beTh[c] = th_b[c] + red[0];
      __syncthreads();
    }
    {
      float s = g_bng[t] * rsqrtf(g_bnv[t] + 1e-5f);
      float d = g_bnb[t] - g_bnm[t] * s;
      float w = g_w[c*256 + t];
      GP[c*256 + t] = (f16)(w * s);
      red[tid] = w * d; __syncthreads();
      for (int o = 128; o > 0; o >>= 1){ if (tid < o) red[tid] += red[tid+o]; __syncthreads(); }
      if (tid == 0) beG[c] = g_b[c] + red[0];
      __syncthreads();
    }
    {
      float s = ph_bng[t] * rsqrtf(ph_bnv[t] + 1e-5f);
      float d = ph_bnb[t] - ph_bnm[t] * s;
      float w = ph_w[c*256 + t];
      PhP[c*256 + t] = (f16)(w * s);
      red[tid] = w * d; __syncthreads();
      for (int o = 128; o > 0; o >>= 1){ if (tid < o) red[tid] += red[tid+o]; __syncthreads(); }
      if (tid == 0) bePh[c] = ph_b[c] + red[0];
    }
  } else {
    const int t = (b - 128) * 2 + (tid >> 7);
    const int c = tid & 127;
    float s = W_bng[t] * rsqrtf(W_bnv[t] + 1e-5f);
    WP[t*128 + c] = f2bf(W_w[t*128 + c] * s);
    if (c == 0) bwe[t] = (W_b[t] - W_bnm[t]) * s + W_bnb[t];
  }
}

__global__ void prep_scalars(
    const float* __restrict__ W_w,
    const float* __restrict__ W_bng, const float* __restrict__ W_bnv,
    char* __restrict__ ws)
{
  const int tid = threadIdx.x;
  float* csw = (float*)(ws + wCsw); float* bwsum = (float*)(ws + wBwsum);
  const float* bwe = (const float*)(ws + wBwe);
  if (tid < 128){
    float a = 0.f;
    for (int t = 0; t < 256; ++t){
      float s = W_bng[t] * rsqrtf(W_bnv[t] + 1e-5f);
      a += W_w[t*128 + tid] * s;
    }
    csw[tid] = a;
  } else if (tid == 128){
    float a = 0.f;
    for (int t = 0; t < 256; ++t) a += bwe[t];
    bwsum[0] = a;
  }
}

// =================== main kernel: 1024 blocks x 1 batch, 16 waves ===================
__global__ __launch_bounds__(NT, 1)
void stacif_main(const float* __restrict__ x1g, const float* __restrict__ x2g,
                 const char* __restrict__ ws, float* __restrict__ outg)
{
  extern __shared__ f16 sm[];
  float* Sf = (float*)(sm + SBASE);
  const int tid = threadIdx.x, bid = blockIdx.x;
  const int wid = tid >> 6, l = tid & 63;
  const float* __restrict__ x1b = x1g + (size_t)bid * BTV;
  const float* __restrict__ x2b = x2g + (size_t)bid * BTV;
  const f16* ThP = (const f16*)(ws + wThP);
  const f16* GP  = (const f16*)(ws + wGP);
  const f16* PhP = (const f16*)(ws + wPhP);
  const s16* WP  = (const s16*)(ws + wWP);
  const float* beTh = (const float*)(ws + wBeTh);
  const float* beG  = (const float*)(ws + wBeG);
  const float* bePh = (const float*)(ws + wBePh);
  const float* bwe  = (const float*)(ws + wBwe);
  const float* csw  = (const float*)(ws + wCsw);
  const float* bwsum = (const float*)(ws + wBwsum);
  s16* Up  = (s16*)(sm + UT);
  s16* USp = (s16*)(sm + US);

  // per-thread staging coords: thread (tS, qS) owns row tS, v in [qS*23, qS*23+23)
  const int tS = tid >> 2, qS = tid & 3, vB = qS * 23;

  // ---------- Ph0: load x1+x2 (latencies overlap), row-mean, stage BOTH (x2T -> X2 region) ----------
  {
    float r1[23], r2[23];
    const float* p1 = x1b + tS * 90;
    const float* p2 = x2b + tS * 90;
    #pragma unroll
    for (int j = 0; j < 23; ++j){
      int off = vB + j; off = (off < 90) ? off : 89;
      r1[j] = p1[off];
    }
    #pragma unroll
    for (int j = 0; j < 23; ++j){
      int off = vB + j; off = (off < 90) ? off : 89;
      r2[j] = p2[off];
    }
    float a = 0.f;
    #pragma unroll
    for (int j = 0; j < 23; ++j) if (vB + j < 90) a += r1[j];
    a += __shfl_xor(a, 1); a += __shfl_xor(a, 2);
    if (qS == 0) Sf[oX1MV + tS] = a * (1.f/90.f);
    #pragma unroll
    for (int j = 0; j < 23; ++j){
      int v = vB + j;
      if (v < 90){
        sm[XT + v*272 + tS] = (f16)r1[j];
        sm[X2 + v*272 + tS] = (f16)r2[j];
      }
    }
  }
  __syncthreads();

  // ---------- Ph1: proj thetaT (waves 0-7) / g1T (waves 8-15): 1 c-tile/wave ----------
  {
    const int mat = wid >> 3;
    const int c0 = (wid & 7) * 16;
    const f16* Wm = mat ? GP : ThP;
    const float* beg = mat ? beG : beTh;
    f32x4 acc[6] = {};
    #pragma unroll
    for (int kk = 0; kk < 8; ++kk){
      f16x8 bfr = frag_ld(Wm + c0*256 + kk*32, 256);   // one L2 B-frag, reused 6x
      #pragma unroll
      for (int vt = 0; vt < 6; ++vt){
        f16x8 a = frag_ld(sm + XT + vt*16*272 + kk*32, 272);
        acc[vt] = MFMA16(a, bfr, acc[vt]);
      }
    }
    int c = c0 + (l & 15);
    float bias = beg[c];
    #pragma unroll
    for (int vt = 0; vt < 6; ++vt){
      #pragma unroll
      for (int r = 0; r < 4; ++r){
        int v = vt*16 + (l >> 4)*4 + r;
        float val = acc[vt][r] + bias;
        if (mat) ((s16*)(sm + G1T))[v*136 + c] = (v < VV) ? f2bf(val) : (s16)0;
        else     sm[THT + v*136 + c] = (v < VV) ? (f16)val : (f16)0.0f;
      }
    }
  }
  __syncthreads();

  // ---------- Ph3: x2 col means (X2) + proj phiT / g2T from X2; mid-barrier before overwrite ----------
  if (tid < 768){
    int v = tid >> 3, p = tid & 7;
    float a = 0.f;
    for (int j = 0; j < 32; ++j) a += (float)sm[X2 + v*272 + p*32 + j];
    a += __shfl_xor(a, 1); a += __shfl_xor(a, 2); a += __shfl_xor(a, 4);
    if (p == 0 && v < VV) Sf[oX2MT + v] = a * (1.f/256.f);
  }
  {
    const int mat = wid >> 3;
    const int c0 = (wid & 7) * 16;
    const f16* Wm = mat ? GP : PhP;
    const float* beg = mat ? beG : bePh;
    f32x4 acc[6] = {};
    #pragma unroll
    for (int kk = 0; kk < 8; ++kk){
      f16x8 bfr = frag_ld(Wm + c0*256 + kk*32, 256);
      #pragma unroll
      for (int vt = 0; vt < 6; ++vt){
        f16x8 a = frag_ld(sm + X2 + vt*16*272 + kk*32, 272);
        acc[vt] = MFMA16(a, bfr, acc[vt]);
      }
    }
    __syncthreads();   // all X2 reads (col-means + frags) complete before PHT/G2T overwrite
    int c = c0 + (l & 15);
    float bias = beg[c];
    #pragma unroll
    for (int vt = 0; vt < 6; ++vt){
      #pragma unroll
      for (int r = 0; r < 4; ++r){
        int v = vt*16 + (l >> 4)*4 + r;
        float val = acc[vt][r] + bias;
        if (mat) ((s16*)(sm + G2T))[v*136 + c] = (v < VV) ? f2bf(val) : (s16)0;
        else     sm[PHT + v*136 + c] = (v < VV) ? (f16)val : (f16)0.0f;
      }
    }
  }
  __syncthreads();

  // ---------- Ph45: waves 0-7: E_t + row softmax + col-partial-max; 8-13: E_s (+M_s partials) ----------
  if (wid < 8){
    int c0 = wid * 16;
    int ca = c0 + (l & 15);
    f32x4 acc[8] = {};
    for (int kk = 0; kk < 3; ++kk){
      int vb = kk*32 + (l >> 4) * 8;
      f16x8 a;
      #pragma unroll
      for (int bb = 0; bb < 8; ++bb) a[bb] = sm[THT + (vb + bb)*136 + ca];
      #pragma unroll
      for (int dt = 0; dt < 8; ++dt){
        int da = dt*16 + (l & 15);
        f16x8 bf;
        #pragma unroll
        for (int bb = 0; bb < 8; ++bb) bf[bb] = sm[PHT + (vb + bb)*136 + da];
        acc[dt] = MFMA16(a, bf, acc[dt]);
      }
    }
    #pragma unroll
    for (int dt = 0; dt < 8; ++dt){
      float m4 = fmaxf(fmaxf(acc[dt][0], acc[dt][1]), fmaxf(acc[dt][2], acc[dt][3]));
      m4 = fmaxf(m4, __shfl_xor(m4, 16));
      m4 = fmaxf(m4, __shfl_xor(m4, 32));
      if (l < 16) Up[(dt*16 + l)*136 + 128 + wid] = f2bf(m4);
    }
    #pragma unroll
    for (int r = 0; r < 4; ++r){
      float m = -3e38f;
      #pragma unroll
      for (int dt = 0; dt < 8; ++dt) m = fmaxf(m, acc[dt][r]);
      for (int sh = 1; sh < 16; sh <<= 1) m = fmaxf(m, __shfl_xor(m, sh));
      float s = 0.f;
      #pragma unroll
      for (int dt = 0; dt < 8; ++dt){ float e = __expf(acc[dt][r] - m); acc[dt][r] = e; s += e; }
      for (int sh = 1; sh < 16; sh <<= 1) s += __shfl_xor(s, sh);
      int row = c0 + (l >> 4)*4 + r;
      if ((l & 15) == 0){ Sf[oMRT + row] = m; Sf[oISRT + row] = 1.f / s; }
      #pragma unroll
      for (int dt = 0; dt < 8; ++dt) Up[row*136 + dt*16 + (l & 15)] = f2bf(acc[dt][r]);
    }
  } else if (wid < 14){
    int v0 = (wid - 8) * 16;
    f32x4 acc[6] = {};
    for (int kk = 0; kk < 4; ++kk){
      f16x8 a = frag_ld(sm + THT + v0*136 + kk*32, 136);
      #pragma unroll
      for (int wt = 0; wt < 6; ++wt){
        f16x8 bfr = frag_ld(sm + PHT + wt*16*136 + kk*32, 136);
        acc[wt] = MFMA16(a, bfr, acc[wt]);
      }
    }
    float wmax = -3e38f;
    #pragma unroll
    for (int r = 0; r < 4; ++r){
      float m = 0.f;   // pad cols are exactly 0
      #pragma unroll
      for (int wt = 0; wt < 6; ++wt) m = fmaxf(m, acc[wt][r]);
      for (int sh = 1; sh < 16; sh <<= 1) m = fmaxf(m, __shfl_xor(m, sh));
      float s = 0.f;
      #pragma unroll
      for (int wt = 0; wt < 6; ++wt){
        float e = __expf(acc[wt][r] - m);
        bool valid = (wt*16 + (l & 15)) < VV;
        acc[wt][r] = valid ? e : 0.f;
        s += acc[wt][r];
      }
      for (int sh = 1; sh < 16; sh <<= 1) s += __shfl_xor(s, sh);
      int row = v0 + (l >> 4)*4 + r;
      if ((l & 15) == 0){ Sf[oMRS + row] = m; Sf[oISRS + row] = 1.f / s; }
      if (row < VV) wmax = fmaxf(wmax, m);
      if (row < VV){
        #pragma unroll
        for (int wt = 0; wt < 6; ++wt) USp[row*96 + wt*16 + (l & 15)] = f2bf(acc[wt][r]);
      }
    }
    wmax = fmaxf(wmax, __shfl_xor(wmax, 16));
    wmax = fmaxf(wmax, __shfl_xor(wmax, 32));
    if (l == 0) Sf[oMSP + (wid - 8)] = wmax;
  }
  __syncthreads();

  // ---------- Phase A: Et col partial sums (conflict-free remap) + Es col sums + M_s ----------
  {
    int ch = wid >> 1;
    int c = (wid & 1) * 64 + l;
    bf16x8 pm8 = *(const bf16x8*)(Up + c*136 + 128);
    float mp = bf2f(pm8[0]);
    #pragma unroll
    for (int q = 1; q < 8; ++q) mp = fmaxf(mp, bf2f(pm8[q]));
    float s = 0.f;
    #pragma unroll
    for (int j = 0; j < 16; ++j){
      int d = ch*16 + j;
      float u = bf2f(Up[d*136 + c]);
      if (u > 0.f){
        float e1 = __expf(0.5f * (Sf[oMRT + d] - mp));
        s += (u * e1) * e1;
      }
    }
    float* PT = (float*)(sm + THT);   // THT dead after Ph45; scratch
    PT[ch*128 + c] = s;
    if (ch == 0) PT[1024 + c] = mp;
  }
  if (tid < 768){
    int v = tid >> 3, p = tid & 7;
    float Ms = Sf[oMSP + 0];
    #pragma unroll
    for (int q = 1; q < 6; ++q) Ms = fmaxf(Ms, Sf[oMSP + q]);
    float s = 0.f;
    for (int j = 0; j < 12; ++j){
      int w = p*12 + j;
      if (w < VV){
        float u = bf2f(USp[w*96 + v]);
        if (u > 0.f) s += u * __expf(Sf[oMRS + w] - Ms);
      }
    }
    s += __shfl_xor(s, 1); s += __shfl_xor(s, 2); s += __shfl_xor(s, 4);
    if (p == 0) Sf[oISCS + v] = 1.f / fmaxf(s, 1e-30f);
  }
  if (tid == 0){
    float Ms = Sf[oMSP + 0];
    #pragma unroll
    for (int q = 1; q < 6; ++q) Ms = fmaxf(Ms, Sf[oMSP + q]);
    Sf[oSCAL + 8] = Ms;
  }
  __syncthreads();
  // ---------- Phase B: finalize Et col stats ----------
  if (tid < 128){
    const float* PT = (const float*)(sm + THT);
    float s = 0.f;
    #pragma unroll
    for (int q = 0; q < 8; ++q) s += PT[q*128 + tid];
    Sf[oMCT + tid] = PT[1024 + tid];
    Sf[oISCT + tid] = 1.f / s;
  }
  __syncthreads();

  // ---------- Ph7: M1 (waves 0-7), M2 (waves 8-15) ----------
  if (wid < 8){
    int c0 = wid * 16;
    const s16* G1 = (const s16*)(sm + G1T);
    s16* M1 = (s16*)(sm + M1o);
    int ca = c0 + (l & 15);
    float mctc = Sf[oMCT + ca];
    f32x4 acc[6] = {};
    #pragma unroll
    for (int kk = 0; kk < 4; ++kk){
      int db = kk*32 + (l >> 4) * 8;
      bf16x8 a;
      #pragma unroll
      for (int bb = 0; bb < 8; ++bb){
        float u = bf2f(Up[(db + bb)*136 + ca]);
        float val = 0.f;
        if (u > 0.f){
          float e1 = __expf(0.5f * (Sf[oMRT + db + bb] - mctc));
          val = (u * e1) * e1;
        }
        a[bb] = f2bf(val);
      }
      #pragma unroll
      for (int vt = 0; vt < 6; ++vt){
        bf16x8 bfv = bfrag_ld(G1 + vt*16*136 + kk*32, 136);
        acc[vt] = MFMABF(a, bfv, acc[vt]);
      }
    }
    #pragma unroll
    for (int vt = 0; vt < 6; ++vt){
      int v = vt*16 + (l & 15);
      float cs = (v < VV) ? Sf[oISRS + v] : 0.f;
      #pragma unroll
      for (int r = 0; r < 4; ++r){
        int c = c0 + (l >> 4)*4 + r;
        M1[c*96 + v] = f2bf(acc[vt][r] * Sf[oISCT + c] * cs);
      }
    }
  } else {
    int c0 = (wid - 8) * 16;
    const s16* G2 = (const s16*)(sm + G2T);
    s16* M2 = (s16*)(sm + M2o);
    f32x4 acc[6] = {};
    #pragma unroll
    for (int kk = 0; kk < 4; ++kk){
      bf16x8 a = bfrag_ld(Up + c0*136 + kk*32, 136);
      #pragma unroll
      for (int vt = 0; vt < 6; ++vt){
        bf16x8 bfv = bfrag_ld(G2 + vt*16*136 + kk*32, 136);
        acc[vt] = MFMABF(a, bfv, acc[vt]);
      }
    }
    #pragma unroll
    for (int vt = 0; vt < 6; ++vt){
      int v = vt*16 + (l & 15);
      float cs = (v < VV) ? Sf[oISCS + v] : 0.f;
      #pragma unroll
      for (int r = 0; r < 4; ++r){
        int c = c0 + (l >> 4)*4 + r;
        M2[c*96 + v] = f2bf(acc[vt][r] * Sf[oISRT + c] * cs);
      }
    }
  }
  __syncthreads();

  // ---------- Ph8: z1T / z2T — 48 balanced units ----------
  for (int pass = 0; pass < 3; ++pass){
    int u = wid + pass*16;          // 0..47
    bool isZ2 = u >= 24;
    int rem = isZ2 ? u - 24 : u;    // 0..23
    int w0 = (rem >> 2) * 16;       // 6 w-tiles
    int cq = rem & 3;               // 4 col-quarters, 2 ct each
    int wa = w0 + (l & 15);
    const s16* Mx = (const s16*)(sm + (isZ2 ? M2o : M1o));
    s16* Z = (s16*)(sm + (isZ2 ? Z2o : Z1o));
    int wr = (wa < VV) ? wa : (VV - 1);
    float e_row = isZ2 ? __expf(Sf[oMRS + wr] - Sf[oSCAL + 8]) : 0.f;
    f32x4 acc[2] = {};
    #pragma unroll
    for (int kk = 0; kk < 3; ++kk){
      int vb = kk*32 + (l >> 4) * 8;
      bf16x8 a;
      if (!isZ2){
        #pragma unroll
        for (int bb = 0; bb < 8; ++bb){
          int v = vb + bb;
          a[bb] = (v < VV) ? USp[v*96 + wa] : (s16)0;
        }
      } else {
        const s16* up = USp + wr*96 + vb;
        #pragma unroll
        for (int bb = 0; bb < 8; ++bb){
          a[bb] = f2bf(bf2f(up[bb]) * e_row);
        }
      }
      #pragma unroll
      for (int ct = 0; ct < 2; ++ct){
        bf16x8 bfv = bfrag_ld(Mx + (cq*2 + ct)*16*96 + kk*32, 96);
        acc[ct] = MFMABF(a, bfv, acc[ct]);
      }
    }
    #pragma unroll
    for (int ct = 0; ct < 2; ++ct){
      #pragma unroll
      for (int r = 0; r < 4; ++r){
        int row = w0 + (l >> 4)*4 + r;
        Z[row*136 + (cq*2 + ct)*16 + (l & 15)] = f2bf(acc[ct][r]);
      }
    }
  }
  __syncthreads();

  // ---------- Ph9a: z column sums ----------
  {
    int col = tid >> 3, zi = (tid >> 2) & 1, p = tid & 3;
    const s16* Z = (const s16*)(sm + (zi ? Z2o : Z1o));
    float s = 0.f;
    for (int j = 0; j < 23; ++j){
      int w = p*23 + j;
      if (w < VV) s += bf2f(Z[w*136 + col]);
    }
    s += __shfl_xor(s, 1); s += __shfl_xor(s, 2);
    if (p == 0){
      float* R = Sf + (zi ? oRED2 : oRED1);
      R[col] = csw[col] * s;
    }
  }
  __syncthreads();
  // ---------- Ph9b (merged): wave 0 does all reductions + fusion weights ----------
  if (wid == 0){
    float s1 = Sf[oRED1 + l] + Sf[oRED1 + 64 + l];
    float s2 = Sf[oRED2 + l] + Sf[oRED2 + 64 + l];
    float t1 = Sf[oX1MV + l] + Sf[oX1MV + 64 + l] + Sf[oX1MV + 128 + l] + Sf[oX1MV + 192 + l];
    float t2 = (l < VV) ? Sf[oX2MT + l] : 0.f;
    if (l < 26) t2 += Sf[oX2MT + 64 + l];
    for (int sh = 1; sh < 64; sh <<= 1){
      s1 += __shfl_xor(s1, sh);
      s2 += __shfl_xor(s2, sh);
      t1 += __shfl_xor(t1, sh);
      t2 += __shfl_xor(t2, sh);
    }
    if (l == 0){
      float m1 = t1 * (1.f/256.f);
      float m2 = t2 * (1.f/90.f);
      float bws = bwsum[0];
      float mp1 = (s1 + 90.f*bws) * (1.f/23040.f);
      float mp2 = (s2 + 90.f*bws) * (1.f/23040.f);
      {
        float mx = fmaxf(m1, fmaxf(m2, mp1));
        float e0 = __expf(m1-mx), e1 = __expf(m2-mx), e2 = __expf(mp1-mx);
        float inv = 1.f/(e0+e1+e2);
        Sf[oSCAL+0] = e0*inv; Sf[oSCAL+1] = e1*inv; Sf[oSCAL+2] = e2*inv;
      }
      {
        float mx = fmaxf(m2, fmaxf(m1, mp2));
        float e0 = __expf(m2-mx), e1 = __expf(m1-mx), e2 = __expf(mp2-mx);
        float inv = 1.f/(e0+e1+e2);
        Sf[oSCAL+3] = e0*inv; Sf[oSCAL+4] = e1*inv; Sf[oSCAL+5] = e2*inv;
      }
    }
  }
  __syncthreads();

  // ---------- Ph10: proj + fuse -> f16 LDS staging (OS1/OS2) ----------
  for (int pass = 0; pass < 2; ++pass){
    int u = wid + pass*16;
    bool is2 = u & 1;
    int t0 = (u >> 1) * 16;
    const s16* Zp = (const s16*)(sm + (is2 ? Z2o : Z1o));
    f32x4 acc[6] = {};
    #pragma unroll
    for (int kk = 0; kk < 4; ++kk){
      bf16x8 a = bfrag_ld(WP + t0*128 + kk*32, 128);
      #pragma unroll
      for (int vt = 0; vt < 6; ++vt){
        bf16x8 bfr = bfrag_ld(Zp + vt*16*136 + kk*32, 136);
        acc[vt] = MFMABF(a, bfr, acc[vt]);
      }
    }
    const float* xb = is2 ? x2b : x1b;
    f16* OS = sm + (is2 ? OS2 : OS1);
    float wa = is2 ? Sf[oSCAL+3] : Sf[oSCAL+0];
    float wb = is2 ? Sf[oSCAL+4] : Sf[oSCAL+1];
    float wc = is2 ? Sf[oSCAL+5] : Sf[oSCAL+2];
    #pragma unroll
    for (int r = 0; r < 4; ++r){
      int t = t0 + (l >> 4)*4 + r;
      float bw = bwe[t];
      float crossv = is2 ? Sf[oX1MV + t] : 0.f;
      #pragma unroll
      for (int vt = 0; vt < 6; ++vt){
        int v = vt*16 + (l & 15);
        if (v < VV){
          float cross = is2 ? crossv : Sf[oX2MT + v];
          OS[t*90 + v] = (f16)(wa * xb[t*90 + v] + wb * cross + wc * (acc[vt][r] + bw));
        }
      }
    }
  }
  __syncthreads();

  // ---------- Ph11: coalesced flush (float4 stores) ----------
  {
    float* out1 = outg + (size_t)bid * BTV;
    float* out2 = outg + (size_t)NB * BTV + (size_t)bid * BTV;
    #pragma unroll
    for (int k = 0; k < 3; ++k){
      int e = (k*1024 + tid) * 8;
      if (e < BTV){
        f16x8 h1 = *(const f16x8*)(sm + OS1 + e);
        f16x8 h2 = *(const f16x8*)(sm + OS2 + e);
        float4 a1 = {h1[0], h1[1], h1[2], h1[3]};
        float4 b1 = {h1[4], h1[5], h1[6], h1[7]};
        float4 a2 = {h2[0], h2[1], h2[2], h2[3]};
        float4 b2 = {h2[4], h2[5], h2[6], h2[7]};
        *(float4*)(out1 + e)     = a1;
        *(float4*)(out1 + e + 4) = b1;
        *(float4*)(out2 + e)     = a2;
        *(float4*)(out2 + e + 4) = b2;
      }
    }
  }
}

} // namespace

extern "C" void kernel_launch(void* const* d_in, const int* in_sizes, int n_in,
                              void* d_out, int out_size, void* d_ws, size_t ws_size,
                              hipStream_t stream)
{
  (void)in_sizes; (void)n_in; (void)out_size; (void)ws_size;
  hipFuncSetAttribute((const void*)stacif_main,
                      hipFuncAttributeMaxDynamicSharedMemorySize, SMEM_BYTES);

  const float* x1 = (const float*)d_in[0];
  const float* x2 = (const float*)d_in[1];
  const float* g_bng = (const float*)d_in[2];
  const float* g_bnb = (const float*)d_in[3];
  const float* g_bnm = (const float*)d_in[4];
  const float* g_bnv = (const float*)d_in[5];
  const float* g_w   = (const float*)d_in[6];
  const float* g_b   = (const float*)d_in[7];
  const float* th_bng = (const float*)d_in[8];
  const float* th_bnb = (const float*)d_in[9];
  const float* th_bnm = (const float*)d_in[10];
  const float* th_bnv = (const float*)d_in[11];
  const float* th_w   = (const float*)d_in[12];
  const float* th_b   = (const float*)d_in[13];
  const float* ph_bng = (const float*)d_in[14];
  const float* ph_bnb = (const float*)d_in[15];
  const float* ph_bnm = (const float*)d_in[16];
  const float* ph_bnv = (const float*)d_in[17];
  const float* ph_w   = (const float*)d_in[18];
  const float* ph_b   = (const float*)d_in[19];
  const float* W_w    = (const float*)d_in[20];
  const float* W_b    = (const float*)d_in[21];
  const float* W_bng  = (const float*)d_in[22];
  const float* W_bnb  = (const float*)d_in[23];
  const float* W_bnm  = (const float*)d_in[24];
  const float* W_bnv  = (const float*)d_in[25];
  char* ws = (char*)d_ws;
  float* out = (float*)d_out;

  prep_weights<<<dim3(256), dim3(256), 0, stream>>>(
      th_w, th_b, th_bng, th_bnb, th_bnm, th_bnv,
      g_w, g_b, g_bng, g_bnb, g_bnm, g_bnv,
      ph_w, ph_b, ph_bng, ph_bnb, ph_bnm, ph_bnv,
      W_w, W_b, W_bng, W_bnb, W_bnm, W_bnv, ws);
  prep_scalars<<<dim3(1), dim3(256), 0, stream>>>(W_w, W_bng, W_bnv, ws);
  stacif_main<<<dim3(NB), dim3(NT), SMEM_BYTES, stream>>>(x1, x2, ws, out);
}

// Round 13
// 257.586 us; speedup vs baseline: 1.1636x; 1.1636x over previous
//
#include <hip/hip_runtime.h>

typedef unsigned int u32;
typedef _Float16 f16;
typedef short s16;
typedef _Float16 f16x8 __attribute__((ext_vector_type(8)));
typedef short bf16x8 __attribute__((ext_vector_type(8)));
typedef float f32x4 __attribute__((ext_vector_type(4)));

#define MFMA16(a,b,c) __builtin_amdgcn_mfma_f32_16x16x32_f16(a,b,c,0,0,0)
#define MFMABF(a,b,c) __builtin_amdgcn_mfma_f32_16x16x32_bf16(a,b,c,0,0,0)

namespace {

constexpr int VV = 90, BTV = 256*90, NB = 1024, NT = 1024;

// ---- LDS layout (2-byte-element offsets) ----
constexpr int XT  = 0;         // f16 [96][272] x1T staging
constexpr int UT  = 0;         // bf16 [128][136] (cols<128 XOR-swizzled); cols 128..135 raw col-partial-max
constexpr int OS1 = 0;         // f16 [256][90] out1 staging (Ph10: UT/US dead)
constexpr int US  = 17408;     // bf16 [90][96]
constexpr int G1T = 26112;     // bf16 [96][136]
constexpr int THT = 39168;     // f16 [96][136] swizzled; f32 scratch after Ph45
constexpr int OS2 = 39168;     // f16 [256][90] out2 staging (M1/M2 dead), ends 62208
constexpr int PHT = 52224;     // f16 [96][136] swizzled
constexpr int X2  = 52224;     // f16 [96][272] x2T staging (over PHT+G2T; dead until Ph3 epilogue)
constexpr int G2T = 65280;     // bf16 [96][136]  (ends 78336)
constexpr int M1o = 39168;     // bf16 [128][96]  over THT
constexpr int M2o = 51456;     // bf16 [128][96]
constexpr int Z1o = 26112;     // bf16 [96][136]  over G1T
constexpr int Z2o = 65280;     // bf16 [96][136]  over G2T
constexpr int SBASE = 78336;   // f32 stats area
constexpr int oX1MV=0, oX2MT=256, oMRT=352, oISRT=480, oMCT=608, oISCT=736,
              oMRS=864, oISRS=960, oMCS=1056, oISCS=1152, oRED1=1248, oRED2=1376, oSCAL=1504;
// oSCAL: 0..5 fusion weights, 8=M_s
constexpr int oMSP = 1520;     // 6 per-wave E_s row-max partials
constexpr int SWORDS = 1536;
constexpr int SMEM_BYTES = SBASE*2 + SWORDS*4;   // 162816 <= 163840

// ---- ws layout (bytes) ----
constexpr size_t wThP=0, wGP=65536, wPhP=131072, wWP=196608,
  wBeTh=262144, wBeG=262656, wBePh=263168, wBwe=263680, wCsw=264704, wBwsum=265216;

// XOR swizzle: spreads 8-apart row groups across disjoint bank windows.
// col must be < 128 (closed under XOR of bits 4..6); preserves 16B chunk alignment.
__device__ __forceinline__ int swz(int row, int col){
  return col ^ (((row >> 3) & 3) << 4);
}

__device__ __forceinline__ f16x8 frag_ld(const f16* p, int stride){
  int l = threadIdx.x & 63;
  return *(const f16x8*)(p + (l & 15) * stride + (l >> 4) * 8);
}
__device__ __forceinline__ bf16x8 bfrag_ld(const s16* p, int stride){
  int l = threadIdx.x & 63;
  return *(const bf16x8*)(p + (l & 15) * stride + (l >> 4) * 8);
}
// swizzled fragment loaders (per-lane row-dependent column XOR)
__device__ __forceinline__ f16x8 frag_ld_sw(const f16* p, int stride, int rowbase, int colbase){
  int l = threadIdx.x & 63;
  int row = rowbase + (l & 15);
  int col = (colbase + (l >> 4) * 8) ^ (((row >> 3) & 3) << 4);
  return *(const f16x8*)(p + row * stride + col);
}
__device__ __forceinline__ bf16x8 bfrag_ld_sw(const s16* p, int stride, int rowbase, int colbase){
  int l = threadIdx.x & 63;
  int row = rowbase + (l & 15);
  int col = (colbase + (l >> 4) * 8) ^ (((row >> 3) & 3) << 4);
  return *(const bf16x8*)(p + row * stride + col);
}
__device__ __forceinline__ s16 f2bf(float x){
  u32 u = __float_as_uint(x);
  u += 0x7FFFu + ((u >> 16) & 1u);   // RNE
  return (s16)(u >> 16);
}
__device__ __forceinline__ float bf2f(s16 h){
  return __uint_as_float(((u32)(unsigned short)h) << 16);
}

// =================== prep kernels (unchanged, correct) ===================
__global__ void prep_weights(
    const float* __restrict__ th_w, const float* __restrict__ th_b,
    const float* __restrict__ th_bng, const float* __restrict__ th_bnb,
    const float* __restrict__ th_bnm, const float* __restrict__ th_bnv,
    const float* __restrict__ g_w, const float* __restrict__ g_b,
    const float* __restrict__ g_bng, const float* __restrict__ g_bnb,
    const float* __restrict__ g_bnm, const float* __restrict__ g_bnv,
    const float* __restrict__ ph_w, const float* __restrict__ ph_b,
    const float* __restrict__ ph_bng, const float* __restrict__ ph_bnb,
    const float* __restrict__ ph_bnm, const float* __restrict__ ph_bnv,
    const float* __restrict__ W_w, const float* __restrict__ W_b,
    const float* __restrict__ W_bng, const float* __restrict__ W_bnb,
    const float* __restrict__ W_bnm, const float* __restrict__ W_bnv,
    char* __restrict__ ws)
{
  __shared__ float red[256];
  const int b = blockIdx.x, tid = threadIdx.x;
  f16* ThP = (f16*)(ws + wThP); f16* GP = (f16*)(ws + wGP);
  f16* PhP = (f16*)(ws + wPhP); s16* WP = (s16*)(ws + wWP);
  float* beTh = (float*)(ws + wBeTh); float* beG = (float*)(ws + wBeG);
  float* bePh = (float*)(ws + wBePh); float* bwe = (float*)(ws + wBwe);
  if (b < 128){
    const int c = b, t = tid;
    {
      float s = th_bng[t] * rsqrtf(th_bnv[t] + 1e-5f);
      float d = th_bnb[t] - th_bnm[t] * s;
      float w = th_w[c*256 + t];
      ThP[c*256 + t] = (f16)(w * s);
      red[tid] = w * d; __syncthreads();
      for (int o = 128; o > 0; o >>= 1){ if (tid < o) red[tid] += red[tid+o]; __syncthreads(); }
      if (tid == 0) beTh[c] = th_b[c] + red[0];
      __syncthreads();
    }
    {
      float s = g_bng[t] * rsqrtf(g_bnv[t] + 1e-5f);
      float d = g_bnb[t] - g_bnm[t] * s;
      float w = g_w[c*256 + t];
      GP[c*256 + t] = (f16)(w * s);
      red[tid] = w * d; __syncthreads();
      for (int o = 128; o > 0; o >>= 1){ if (tid < o) red[tid] += red[tid+o]; __syncthreads(); }
      if (tid == 0) beG[c] = g_b[c] + red[0];
      __syncthreads();
    }
    {
      float s = ph_bng[t] * rsqrtf(ph_bnv[t] + 1e-5f);
      float d = ph_bnb[t] - ph_bnm[t] * s;
      float w = ph_w[c*256 + t];
      PhP[c*256 + t] = (f16)(w * s);
      red[tid] = w * d; __syncthreads();
      for (int o = 128; o > 0; o >>= 1){ if (tid < o) red[tid] += red[tid+o]; __syncthreads(); }
      if (tid == 0) bePh[c] = ph_b[c] + red[0];
    }
  } else {
    const int t = (b - 128) * 2 + (tid >> 7);
    const int c = tid & 127;
    float s = W_bng[t] * rsqrtf(W_bnv[t] + 1e-5f);
    WP[t*128 + c] = f2bf(W_w[t*128 + c] * s);
    if (c == 0) bwe[t] = (W_b[t] - W_bnm[t]) * s + W_bnb[t];
  }
}

__global__ void prep_scalars(
    const float* __restrict__ W_w,
    const float* __restrict__ W_bng, const float* __restrict__ W_bnv,
    char* __restrict__ ws)
{
  const int tid = threadIdx.x;
  float* csw = (float*)(ws + wCsw); float* bwsum = (float*)(ws + wBwsum);
  const float* bwe = (const float*)(ws + wBwe);
  if (tid < 128){
    float a = 0.f;
    for (int t = 0; t < 256; ++t){
      float s = W_bng[t] * rsqrtf(W_bnv[t] + 1e-5f);
      a += W_w[t*128 + tid] * s;
    }
    csw[tid] = a;
  } else if (tid == 128){
    float a = 0.f;
    for (int t = 0; t < 256; ++t) a += bwe[t];
    bwsum[0] = a;
  }
}

// =================== main kernel: 1024 blocks x 1 batch, 16 waves ===================
__global__ __launch_bounds__(NT, 1)
void stacif_main(const float* __restrict__ x1g, const float* __restrict__ x2g,
                 const char* __restrict__ ws, float* __restrict__ outg)
{
  extern __shared__ f16 sm[];
  float* Sf = (float*)(sm + SBASE);
  const int tid = threadIdx.x, bid = blockIdx.x;
  const int wid = tid >> 6, l = tid & 63;
  const float* __restrict__ x1b = x1g + (size_t)bid * BTV;
  const float* __restrict__ x2b = x2g + (size_t)bid * BTV;
  const f16* ThP = (const f16*)(ws + wThP);
  const f16* GP  = (const f16*)(ws + wGP);
  const f16* PhP = (const f16*)(ws + wPhP);
  const s16* WP  = (const s16*)(ws + wWP);
  const float* beTh = (const float*)(ws + wBeTh);
  const float* beG  = (const float*)(ws + wBeG);
  const float* bePh = (const float*)(ws + wBePh);
  const float* bwe  = (const float*)(ws + wBwe);
  const float* csw  = (const float*)(ws + wCsw);
  const float* bwsum = (const float*)(ws + wBwsum);
  s16* Up  = (s16*)(sm + UT);
  s16* USp = (s16*)(sm + US);

  // per-thread staging coords: thread (tS, qS) owns row tS, v in [qS*23, qS*23+23)
  const int tS = tid >> 2, qS = tid & 3, vB = qS * 23;

  // ---------- Ph0: two scopes (<=23 floats live): x1 load+mean+stage, then x2 load+stage ----------
  {
    float r1[23];
    const float* p1 = x1b + tS * 90;
    #pragma unroll
    for (int j = 0; j < 23; ++j){
      int off = vB + j; off = (off < 90) ? off : 89;
      r1[j] = p1[off];
    }
    float a = 0.f;
    #pragma unroll
    for (int j = 0; j < 23; ++j) if (vB + j < 90) a += r1[j];
    a += __shfl_xor(a, 1); a += __shfl_xor(a, 2);
    if (qS == 0) Sf[oX1MV + tS] = a * (1.f/90.f);
    #pragma unroll
    for (int j = 0; j < 23; ++j){
      int v = vB + j;
      if (v < 90) sm[XT + v*272 + tS] = (f16)r1[j];
    }
  }
  {
    float r2[23];
    const float* p2 = x2b + tS * 90;
    #pragma unroll
    for (int j = 0; j < 23; ++j){
      int off = vB + j; off = (off < 90) ? off : 89;
      r2[j] = p2[off];
    }
    #pragma unroll
    for (int j = 0; j < 23; ++j){
      int v = vB + j;
      if (v < 90) sm[X2 + v*272 + tS] = (f16)r2[j];
    }
  }
  __syncthreads();

  // ---------- Ph1: proj thetaT (waves 0-7, swizzled) / g1T (waves 8-15) ----------
  {
    const int mat = wid >> 3;
    const int c0 = (wid & 7) * 16;
    const f16* Wm = mat ? GP : ThP;
    const float* beg = mat ? beG : beTh;
    f32x4 acc[6] = {};
    #pragma unroll
    for (int kk = 0; kk < 8; ++kk){
      f16x8 bfr = frag_ld(Wm + c0*256 + kk*32, 256);
      #pragma unroll
      for (int vt = 0; vt < 6; ++vt){
        f16x8 a = frag_ld(sm + XT + vt*16*272 + kk*32, 272);
        acc[vt] = MFMA16(a, bfr, acc[vt]);
      }
    }
    int c = c0 + (l & 15);
    float bias = beg[c];
    #pragma unroll
    for (int vt = 0; vt < 6; ++vt){
      #pragma unroll
      for (int r = 0; r < 4; ++r){
        int v = vt*16 + (l >> 4)*4 + r;
        float val = acc[vt][r] + bias;
        if (mat) ((s16*)(sm + G1T))[v*136 + c] = (v < VV) ? f2bf(val) : (s16)0;
        else     sm[THT + v*136 + swz(v, c)] = (v < VV) ? (f16)val : (f16)0.0f;
      }
    }
  }
  __syncthreads();

  // ---------- Ph3: x2 col means + proj phiT (swizzled) / g2T; mid-barrier before overwrite ----------
  if (tid < 768){
    int v = tid >> 3, p = tid & 7;
    float a = 0.f;
    for (int j = 0; j < 32; ++j) a += (float)sm[X2 + v*272 + p*32 + j];
    a += __shfl_xor(a, 1); a += __shfl_xor(a, 2); a += __shfl_xor(a, 4);
    if (p == 0 && v < VV) Sf[oX2MT + v] = a * (1.f/256.f);
  }
  {
    const int mat = wid >> 3;
    const int c0 = (wid & 7) * 16;
    const f16* Wm = mat ? GP : PhP;
    const float* beg = mat ? beG : bePh;
    f32x4 acc[6] = {};
    #pragma unroll
    for (int kk = 0; kk < 8; ++kk){
      f16x8 bfr = frag_ld(Wm + c0*256 + kk*32, 256);
      #pragma unroll
      for (int vt = 0; vt < 6; ++vt){
        f16x8 a = frag_ld(sm + X2 + vt*16*272 + kk*32, 272);
        acc[vt] = MFMA16(a, bfr, acc[vt]);
      }
    }
    __syncthreads();   // all X2 reads complete before PHT/G2T overwrite
    int c = c0 + (l & 15);
    float bias = beg[c];
    #pragma unroll
    for (int vt = 0; vt < 6; ++vt){
      #pragma unroll
      for (int r = 0; r < 4; ++r){
        int v = vt*16 + (l >> 4)*4 + r;
        float val = acc[vt][r] + bias;
        if (mat) ((s16*)(sm + G2T))[v*136 + c] = (v < VV) ? f2bf(val) : (s16)0;
        else     sm[PHT + v*136 + swz(v, c)] = (v < VV) ? (f16)val : (f16)0.0f;
      }
    }
  }
  __syncthreads();

  // ---------- Ph45: waves 0-7: E_t + row softmax + col-partial-max; 8-13: E_s (+M_s partials) ----------
  if (wid < 8){
    int c0 = wid * 16;
    int ca = c0 + (l & 15);
    f32x4 acc[8] = {};
    for (int kk = 0; kk < 3; ++kk){
      int vb = kk*32 + (l >> 4) * 8;      // 8-aligned -> swizzle constant across bb
      int cas = swz(vb, ca);
      f16x8 a;
      #pragma unroll
      for (int bb = 0; bb < 8; ++bb) a[bb] = sm[THT + (vb + bb)*136 + cas];
      #pragma unroll
      for (int dt = 0; dt < 8; ++dt){
        int das = swz(vb, dt*16 + (l & 15));
        f16x8 bf;
        #pragma unroll
        for (int bb = 0; bb < 8; ++bb) bf[bb] = sm[PHT + (vb + bb)*136 + das];
        acc[dt] = MFMA16(a, bf, acc[dt]);
      }
    }
    #pragma unroll
    for (int dt = 0; dt < 8; ++dt){
      float m4 = fmaxf(fmaxf(acc[dt][0], acc[dt][1]), fmaxf(acc[dt][2], acc[dt][3]));
      m4 = fmaxf(m4, __shfl_xor(m4, 16));
      m4 = fmaxf(m4, __shfl_xor(m4, 32));
      if (l < 16) Up[(dt*16 + l)*136 + 128 + wid] = f2bf(m4);   // pad cols raw
    }
    #pragma unroll
    for (int r = 0; r < 4; ++r){
      float m = -3e38f;
      #pragma unroll
      for (int dt = 0; dt < 8; ++dt) m = fmaxf(m, acc[dt][r]);
      for (int sh = 1; sh < 16; sh <<= 1) m = fmaxf(m, __shfl_xor(m, sh));
      float s = 0.f;
      #pragma unroll
      for (int dt = 0; dt < 8; ++dt){ float e = __expf(acc[dt][r] - m); acc[dt][r] = e; s += e; }
      for (int sh = 1; sh < 16; sh <<= 1) s += __shfl_xor(s, sh);
      int row = c0 + (l >> 4)*4 + r;
      if ((l & 15) == 0){ Sf[oMRT + row] = m; Sf[oISRT + row] = 1.f / s; }
      #pragma unroll
      for (int dt = 0; dt < 8; ++dt) Up[row*136 + swz(row, dt*16 + (l & 15))] = f2bf(acc[dt][r]);
    }
  } else if (wid < 14){
    int v0 = (wid - 8) * 16;
    f32x4 acc[6] = {};
    for (int kk = 0; kk < 4; ++kk){
      f16x8 a = frag_ld_sw(sm + THT, 136, v0, kk*32);
      #pragma unroll
      for (int wt = 0; wt < 6; ++wt){
        f16x8 bfr = frag_ld_sw(sm + PHT, 136, wt*16, kk*32);
        acc[wt] = MFMA16(a, bfr, acc[wt]);
      }
    }
    float wmax = -3e38f;
    #pragma unroll
    for (int r = 0; r < 4; ++r){
      float m = 0.f;   // pad cols are exactly 0
      #pragma unroll
      for (int wt = 0; wt < 6; ++wt) m = fmaxf(m, acc[wt][r]);
      for (int sh = 1; sh < 16; sh <<= 1) m = fmaxf(m, __shfl_xor(m, sh));
      float s = 0.f;
      #pragma unroll
      for (int wt = 0; wt < 6; ++wt){
        float e = __expf(acc[wt][r] - m);
        bool valid = (wt*16 + (l & 15)) < VV;
        acc[wt][r] = valid ? e : 0.f;
        s += acc[wt][r];
      }
      for (int sh = 1; sh < 16; sh <<= 1) s += __shfl_xor(s, sh);
      int row = v0 + (l >> 4)*4 + r;
      if ((l & 15) == 0){ Sf[oMRS + row] = m; Sf[oISRS + row] = 1.f / s; }
      if (row < VV) wmax = fmaxf(wmax, m);
      if (row < VV){
        #pragma unroll
        for (int wt = 0; wt < 6; ++wt) USp[row*96 + wt*16 + (l & 15)] = f2bf(acc[wt][r]);
      }
    }
    wmax = fmaxf(wmax, __shfl_xor(wmax, 16));
    wmax = fmaxf(wmax, __shfl_xor(wmax, 32));
    if (l == 0) Sf[oMSP + (wid - 8)] = wmax;
  }
  __syncthreads();

  // ---------- Phase A: Et col partial sums + Es col sums + M_s ----------
  {
    int ch = wid >> 1;
    int c = (wid & 1) * 64 + l;
    bf16x8 pm8 = *(const bf16x8*)(Up + c*136 + 128);   // raw pad cols
    float mp = bf2f(pm8[0]);
    #pragma unroll
    for (int q = 1; q < 8; ++q) mp = fmaxf(mp, bf2f(pm8[q]));
    float s = 0.f;
    #pragma unroll
    for (int j = 0; j < 16; ++j){
      int d = ch*16 + j;
      float u = bf2f(Up[d*136 + swz(d, c)]);
      if (u > 0.f){
        float e1 = __expf(0.5f * (Sf[oMRT + d] - mp));
        s += (u * e1) * e1;
      }
    }
    float* PT = (float*)(sm + THT);   // THT dead; scratch
    PT[ch*128 + c] = s;
    if (ch == 0) PT[1024 + c] = mp;
  }
  if (tid < 768){
    int v = tid >> 3, p = tid & 7;
    float Ms = Sf[oMSP + 0];
    #pragma unroll
    for (int q = 1; q < 6; ++q) Ms = fmaxf(Ms, Sf[oMSP + q]);
    float s = 0.f;
    for (int j = 0; j < 12; ++j){
      int w = p*12 + j;
      if (w < VV){
        float u = bf2f(USp[w*96 + v]);
        if (u > 0.f) s += u * __expf(Sf[oMRS + w] - Ms);
      }
    }
    s += __shfl_xor(s, 1); s += __shfl_xor(s, 2); s += __shfl_xor(s, 4);
    if (p == 0) Sf[oISCS + v] = 1.f / fmaxf(s, 1e-30f);
  }
  if (tid == 0){
    float Ms = Sf[oMSP + 0];
    #pragma unroll
    for (int q = 1; q < 6; ++q) Ms = fmaxf(Ms, Sf[oMSP + q]);
    Sf[oSCAL + 8] = Ms;
  }
  __syncthreads();
  // ---------- Phase B: finalize Et col stats ----------
  if (tid < 128){
    const float* PT = (const float*)(sm + THT);
    float s = 0.f;
    #pragma unroll
    for (int q = 0; q < 8; ++q) s += PT[q*128 + tid];
    Sf[oMCT + tid] = PT[1024 + tid];
    Sf[oISCT + tid] = 1.f / s;
  }
  __syncthreads();

  // ---------- Ph7: M1 (waves 0-7), M2 (waves 8-15) ----------
  if (wid < 8){
    int c0 = wid * 16;
    const s16* G1 = (const s16*)(sm + G1T);
    s16* M1 = (s16*)(sm + M1o);
    int ca = c0 + (l & 15);
    float mctc = Sf[oMCT + ca];
    f32x4 acc[6] = {};
    #pragma unroll
    for (int kk = 0; kk < 4; ++kk){
      int db = kk*32 + (l >> 4) * 8;    // 8-aligned -> swizzle constant across bb
      int cas = swz(db, ca);
      bf16x8 a;
      #pragma unroll
      for (int bb = 0; bb < 8; ++bb){
        float u = bf2f(Up[(db + bb)*136 + cas]);
        float val = 0.f;
        if (u > 0.f){
          float e1 = __expf(0.5f * (Sf[oMRT + db + bb] - mctc));
          val = (u * e1) * e1;
        }
        a[bb] = f2bf(val);
      }
      #pragma unroll
      for (int vt = 0; vt < 6; ++vt){
        bf16x8 bfv = bfrag_ld(G1 + vt*16*136 + kk*32, 136);
        acc[vt] = MFMABF(a, bfv, acc[vt]);
      }
    }
    #pragma unroll
    for (int vt = 0; vt < 6; ++vt){
      int v = vt*16 + (l & 15);
      float cs = (v < VV) ? Sf[oISRS + v] : 0.f;
      #pragma unroll
      for (int r = 0; r < 4; ++r){
        int c = c0 + (l >> 4)*4 + r;
        M1[c*96 + v] = f2bf(acc[vt][r] * Sf[oISCT + c] * cs);
      }
    }
  } else {
    int c0 = (wid - 8) * 16;
    const s16* G2 = (const s16*)(sm + G2T);
    s16* M2 = (s16*)(sm + M2o);
    f32x4 acc[6] = {};
    #pragma unroll
    for (int kk = 0; kk < 4; ++kk){
      bf16x8 a = bfrag_ld_sw(Up, 136, c0, kk*32);
      #pragma unroll
      for (int vt = 0; vt < 6; ++vt){
        bf16x8 bfv = bfrag_ld(G2 + vt*16*136 + kk*32, 136);
        acc[vt] = MFMABF(a, bfv, acc[vt]);
      }
    }
    #pragma unroll
    for (int vt = 0; vt < 6; ++vt){
      int v = vt*16 + (l & 15);
      float cs = (v < VV) ? Sf[oISCS + v] : 0.f;
      #pragma unroll
      for (int r = 0; r < 4; ++r){
        int c = c0 + (l >> 4)*4 + r;
        M2[c*96 + v] = f2bf(acc[vt][r] * Sf[oISRT + c] * cs);
      }
    }
  }
  __syncthreads();

  // ---------- Ph8: z1T / z2T — 48 balanced units ----------
  for (int pass = 0; pass < 3; ++pass){
    int u = wid + pass*16;          // 0..47
    bool isZ2 = u >= 24;
    int rem = isZ2 ? u - 24 : u;    // 0..23
    int w0 = (rem >> 2) * 16;       // 6 w-tiles
    int cq = rem & 3;               // 4 col-quarters, 2 ct each
    int wa = w0 + (l & 15);
    const s16* Mx = (const s16*)(sm + (isZ2 ? M2o : M1o));
    s16* Z = (s16*)(sm + (isZ2 ? Z2o : Z1o));
    int wr = (wa < VV) ? wa : (VV - 1);
    float e_row = isZ2 ? __expf(Sf[oMRS + wr] - Sf[oSCAL + 8]) : 0.f;
    f32x4 acc[2] = {};
    #pragma unroll
    for (int kk = 0; kk < 3; ++kk){
      int vb = kk*32 + (l >> 4) * 8;
      bf16x8 a;
      if (!isZ2){
        #pragma unroll
        for (int bb = 0; bb < 8; ++bb){
          int v = vb + bb;
          a[bb] = (v < VV) ? USp[v*96 + wa] : (s16)0;
        }
      } else {
        const s16* up = USp + wr*96 + vb;
        #pragma unroll
        for (int bb = 0; bb < 8; ++bb){
          a[bb] = f2bf(bf2f(up[bb]) * e_row);
        }
      }
      #pragma unroll
      for (int ct = 0; ct < 2; ++ct){
        bf16x8 bfv = bfrag_ld(Mx + (cq*2 + ct)*16*96 + kk*32, 96);
        acc[ct] = MFMABF(a, bfv, acc[ct]);
      }
    }
    #pragma unroll
    for (int ct = 0; ct < 2; ++ct){
      #pragma unroll
      for (int r = 0; r < 4; ++r){
        int row = w0 + (l >> 4)*4 + r;
        Z[row*136 + (cq*2 + ct)*16 + (l & 15)] = f2bf(acc[ct][r]);
      }
    }
  }
  __syncthreads();

  // ---------- Ph9a: z column sums ----------
  {
    int col = tid >> 3, zi = (tid >> 2) & 1, p = tid & 3;
    const s16* Z = (const s16*)(sm + (zi ? Z2o : Z1o));
    float s = 0.f;
    for (int j = 0; j < 23; ++j){
      int w = p*23 + j;
      if (w < VV) s += bf2f(Z[w*136 + col]);
    }
    s += __shfl_xor(s, 1); s += __shfl_xor(s, 2);
    if (p == 0){
      float* R = Sf + (zi ? oRED2 : oRED1);
      R[col] = csw[col] * s;
    }
  }
  __syncthreads();
  // ---------- Ph9b (merged): wave 0 does all reductions + fusion weights ----------
  if (wid == 0){
    float s1 = Sf[oRED1 + l] + Sf[oRED1 + 64 + l];
    float s2 = Sf[oRED2 + l] + Sf[oRED2 + 64 + l];
    float t1 = Sf[oX1MV + l] + Sf[oX1MV + 64 + l] + Sf[oX1MV + 128 + l] + Sf[oX1MV + 192 + l];
    float t2 = (l < VV) ? Sf[oX2MT + l] : 0.f;
    if (l < 26) t2 += Sf[oX2MT + 64 + l];
    for (int sh = 1; sh < 64; sh <<= 1){
      s1 += __shfl_xor(s1, sh);
      s2 += __shfl_xor(s2, sh);
      t1 += __shfl_xor(t1, sh);
      t2 += __shfl_xor(t2, sh);
    }
    if (l == 0){
      float m1 = t1 * (1.f/256.f);
      float m2 = t2 * (1.f/90.f);
      float bws = bwsum[0];
      float mp1 = (s1 + 90.f*bws) * (1.f/23040.f);
      float mp2 = (s2 + 90.f*bws) * (1.f/23040.f);
      {
        float mx = fmaxf(m1, fmaxf(m2, mp1));
        float e0 = __expf(m1-mx), e1 = __expf(m2-mx), e2 = __expf(mp1-mx);
        float inv = 1.f/(e0+e1+e2);
        Sf[oSCAL+0] = e0*inv; Sf[oSCAL+1] = e1*inv; Sf[oSCAL+2] = e2*inv;
      }
      {
        float mx = fmaxf(m2, fmaxf(m1, mp2));
        float e0 = __expf(m2-mx), e1 = __expf(m1-mx), e2 = __expf(mp2-mx);
        float inv = 1.f/(e0+e1+e2);
        Sf[oSCAL+3] = e0*inv; Sf[oSCAL+4] = e1*inv; Sf[oSCAL+5] = e2*inv;
      }
    }
  }
  __syncthreads();

  // ---------- Ph10: proj + (cross,bias) -> f16 LDS staging; x-term deferred to flush ----------
  for (int pass = 0; pass < 2; ++pass){
    int u = wid + pass*16;
    bool is2 = u & 1;
    int t0 = (u >> 1) * 16;
    const s16* Zp = (const s16*)(sm + (is2 ? Z2o : Z1o));
    f32x4 acc[6] = {};
    #pragma unroll
    for (int kk = 0; kk < 4; ++kk){
      bf16x8 a = bfrag_ld(WP + t0*128 + kk*32, 128);
      #pragma unroll
      for (int vt = 0; vt < 6; ++vt){
        bf16x8 bfr = bfrag_ld(Zp + vt*16*136 + kk*32, 136);
        acc[vt] = MFMABF(a, bfr, acc[vt]);
      }
    }
    f16* OS = sm + (is2 ? OS2 : OS1);
    float wb = is2 ? Sf[oSCAL+4] : Sf[oSCAL+1];
    float wc = is2 ? Sf[oSCAL+5] : Sf[oSCAL+2];
    #pragma unroll
    for (int r = 0; r < 4; ++r){
      int t = t0 + (l >> 4)*4 + r;
      float bw = bwe[t];
      float crossv = is2 ? Sf[oX1MV + t] : 0.f;
      #pragma unroll
      for (int vt = 0; vt < 6; ++vt){
        int v = vt*16 + (l & 15);
        if (v < VV){
          float cross = is2 ? crossv : Sf[oX2MT + v];
          OS[t*90 + v] = (f16)(wb * cross + wc * (acc[vt][r] + bw));
        }
      }
    }
  }
  __syncthreads();

  // ---------- Ph11: coalesced flush with x folded in (float4 reads+stores) ----------
  {
    float* out1 = outg + (size_t)bid * BTV;
    float* out2 = outg + (size_t)NB * BTV + (size_t)bid * BTV;
    const float4* x14 = (const float4*)x1b;
    const float4* x24 = (const float4*)x2b;
    float wa1 = Sf[oSCAL+0], wa2 = Sf[oSCAL+3];
    #pragma unroll
    for (int k = 0; k < 3; ++k){
      int e = (k*1024 + tid) * 8;
      if (e < BTV){
        float4 xa = x14[e/4], xb4 = x14[e/4 + 1];
        float4 xc = x24[e/4], xd4 = x24[e/4 + 1];
        f16x8 h1 = *(const f16x8*)(sm + OS1 + e);
        f16x8 h2 = *(const f16x8*)(sm + OS2 + e);
        float4 a1 = {wa1*xa.x + (float)h1[0], wa1*xa.y + (float)h1[1],
                     wa1*xa.z + (float)h1[2], wa1*xa.w + (float)h1[3]};
        float4 b1 = {wa1*xb4.x + (float)h1[4], wa1*xb4.y + (float)h1[5],
                     wa1*xb4.z + (float)h1[6], wa1*xb4.w + (float)h1[7]};
        float4 a2 = {wa2*xc.x + (float)h2[0], wa2*xc.y + (float)h2[1],
                     wa2*xc.z + (float)h2[2], wa2*xc.w + (float)h2[3]};
        float4 b2 = {wa2*xd4.x + (float)h2[4], wa2*xd4.y + (float)h2[5],
                     wa2*xd4.z + (float)h2[6], wa2*xd4.w + (float)h2[7]};
        *(float4*)(out1 + e)     = a1;
        *(float4*)(out1 + e + 4) = b1;
        *(float4*)(out2 + e)     = a2;
        *(float4*)(out2 + e + 4) = b2;
      }
    }
  }
}

} // namespace

extern "C" void kernel_launch(void* const* d_in, const int* in_sizes, int n_in,
                              void* d_out, int out_size, void* d_ws, size_t ws_size,
                              hipStream_t stream)
{
  (void)in_sizes; (void)n_in; (void)out_size; (void)ws_size;
  hipFuncSetAttribute((const void*)stacif_main,
                      hipFuncAttributeMaxDynamicSharedMemorySize, SMEM_BYTES);

  const float* x1 = (const float*)d_in[0];
  const float* x2 = (const float*)d_in[1];
  const float* g_bng = (const float*)d_in[2];
  const float* g_bnb = (const float*)d_in[3];
  const float* g_bnm = (const float*)d_in[4];
  const float* g_bnv = (const float*)d_in[5];
  const float* g_w   = (const float*)d_in[6];
  const float* g_b   = (const float*)d_in[7];
  const float* th_bng = (const float*)d_in[8];
  const float* th_bnb = (const float*)d_in[9];
  const float* th_bnm = (const float*)d_in[10];
  const float* th_bnv = (const float*)d_in[11];
  const float* th_w   = (const float*)d_in[12];
  const float* th_b   = (const float*)d_in[13];
  const float* ph_bng = (const float*)d_in[14];
  const float* ph_bnb = (const float*)d_in[15];
  const float* ph_bnm = (const float*)d_in[16];
  const float* ph_bnv = (const float*)d_in[17];
  const float* ph_w   = (const float*)d_in[18];
  const float* ph_b   = (const float*)d_in[19];
  const float* W_w    = (const float*)d_in[20];
  const float* W_b    = (const float*)d_in[21];
  const float* W_bng  = (const float*)d_in[22];
  const float* W_bnb  = (const float*)d_in[23];
  const float* W_bnm  = (const float*)d_in[24];
  const float* W_bnv  = (const float*)d_in[25];
  char* ws = (char*)d_ws;
  float* out = (float*)d_out;

  prep_weights<<<dim3(256), dim3(256), 0, stream>>>(
      th_w, th_b, th_bng, th_bnb, th_bnm, th_bnv,
      g_w, g_b, g_bng, g_bnb, g_bnm, g_bnv,
      ph_w, ph_b, ph_bng, ph_bnb, ph_bnm, ph_bnv,
      W_w, W_b, W_bng, W_bnb, W_bnm, W_bnv, ws);
  prep_scalars<<<dim3(1), dim3(256), 0, stream>>>(W_w, W_bng, W_bnv, ws);
  stacif_main<<<dim3(NB), dim3(NT), SMEM_BYTES, stream>>>(x1, x2, ws, out);
}

// Round 14
// 240.653 us; speedup vs baseline: 1.2454x; 1.0704x over previous
//
#include <hip/hip_runtime.h>

typedef unsigned int u32;
typedef _Float16 f16;
typedef short s16;
typedef _Float16 f16x8 __attribute__((ext_vector_type(8)));
typedef short bf16x8 __attribute__((ext_vector_type(8)));
typedef float f32x4 __attribute__((ext_vector_type(4)));

#define MFMA16(a,b,c) __builtin_amdgcn_mfma_f32_16x16x32_f16(a,b,c,0,0,0)
#define MFMABF(a,b,c) __builtin_amdgcn_mfma_f32_16x16x32_bf16(a,b,c,0,0,0)

namespace {

constexpr int VV = 90, BTV = 256*90, NB = 1024, NT = 1024;

// ---- LDS layout (2-byte-element offsets) ----
// stride-104 for US/M (52 dwords = 20 mod 32 -> 8 rows cover all banks, 2-way max)
constexpr int XT  = 0;         // f16 [96][272] x1T staging (dead after Ph1)
constexpr int UT  = 0;         // bf16 [128][136] swizzled; cols 128..135 raw col-partial-max
constexpr int OS1 = 0;         // f16 [256][90] out1 staging (Ph10)
constexpr int US  = 17408;     // bf16 [90][104]  (ends 26768)
constexpr int G1T = 26768;     // bf16 [96][136]  (ends 39824)
constexpr int THT = 39824;     // f16 [96][136] swizzled; f32 scratch in Phase A
constexpr int PHT = 52880;     // f16 [96][136] swizzled (ends 65936)
constexpr int X2  = 52880;     // f16 [96][272] x2T staging (ends 78992; dead before PHT/G2T writes)
constexpr int G2T = 66448;     // bf16 [96][136]  (ends 79504)
constexpr int M1o = 39824;     // bf16 [128][104] over THT (ends 53136)
constexpr int M2o = 53136;     // bf16 [128][104] over PHT (ends 66448)
constexpr int Z1o = 26768;     // bf16 [96][136]  over G1T
constexpr int Z2o = 66448;     // bf16 [96][136]  over G2T
constexpr int OS2 = 39824;     // f16 [256][90] out2 staging over M1/M2 (ends 62864)
constexpr int SBASE = 79504;   // f32 stats area (byte 159008)
constexpr int oX1MV=0, oX2MT=256, oMRT=352, oISRT=480, oMCT=608, oISCT=736,
              oMRS=864, oISRS=960, oISCS=1056, oSCAL=1152, oMSP=1168;
constexpr int oRED1=608, oRED2=736;   // overlay MCT/ISCT (dead after Ph7)
constexpr int SWORDS = 1184;
constexpr int SMEM_BYTES = SBASE*2 + SWORDS*4;   // 163744 <= 163840

// ---- ws layout (bytes) ----
constexpr size_t wThP=0, wGP=65536, wPhP=131072, wWP=196608,
  wBeTh=262144, wBeG=262656, wBePh=263168, wBwe=263680, wCsw=264704, wBwsum=265216;

__device__ __forceinline__ int swz(int row, int col){
  return col ^ (((row >> 3) & 3) << 4);
}

__device__ __forceinline__ f16x8 frag_ld(const f16* p, int stride){
  int l = threadIdx.x & 63;
  return *(const f16x8*)(p + (l & 15) * stride + (l >> 4) * 8);
}
__device__ __forceinline__ bf16x8 bfrag_ld(const s16* p, int stride){
  int l = threadIdx.x & 63;
  return *(const bf16x8*)(p + (l & 15) * stride + (l >> 4) * 8);
}
__device__ __forceinline__ f16x8 frag_ld_sw(const f16* p, int stride, int rowbase, int colbase){
  int l = threadIdx.x & 63;
  int row = rowbase + (l & 15);
  int col = (colbase + (l >> 4) * 8) ^ (((row >> 3) & 3) << 4);
  return *(const f16x8*)(p + row * stride + col);
}
__device__ __forceinline__ bf16x8 bfrag_ld_sw(const s16* p, int stride, int rowbase, int colbase){
  int l = threadIdx.x & 63;
  int row = rowbase + (l & 15);
  int col = (colbase + (l >> 4) * 8) ^ (((row >> 3) & 3) << 4);
  return *(const bf16x8*)(p + row * stride + col);
}
__device__ __forceinline__ s16 f2bf(float x){
  u32 u = __float_as_uint(x);
  u += 0x7FFFu + ((u >> 16) & 1u);   // RNE
  return (s16)(u >> 16);
}
__device__ __forceinline__ float bf2f(s16 h){
  return __uint_as_float(((u32)(unsigned short)h) << 16);
}

// =================== single prep kernel (scalars merged in) ===================
__global__ void prep_weights(
    const float* __restrict__ th_w, const float* __restrict__ th_b,
    const float* __restrict__ th_bng, const float* __restrict__ th_bnb,
    const float* __restrict__ th_bnm, const float* __restrict__ th_bnv,
    const float* __restrict__ g_w, const float* __restrict__ g_b,
    const float* __restrict__ g_bng, const float* __restrict__ g_bnb,
    const float* __restrict__ g_bnm, const float* __restrict__ g_bnv,
    const float* __restrict__ ph_w, const float* __restrict__ ph_b,
    const float* __restrict__ ph_bng, const float* __restrict__ ph_bnb,
    const float* __restrict__ ph_bnm, const float* __restrict__ ph_bnv,
    const float* __restrict__ W_w, const float* __restrict__ W_b,
    const float* __restrict__ W_bng, const float* __restrict__ W_bnb,
    const float* __restrict__ W_bnm, const float* __restrict__ W_bnv,
    char* __restrict__ ws)
{
  __shared__ float red[256];
  const int b = blockIdx.x, tid = threadIdx.x;
  f16* ThP = (f16*)(ws + wThP); f16* GP = (f16*)(ws + wGP);
  f16* PhP = (f16*)(ws + wPhP); s16* WP = (s16*)(ws + wWP);
  float* beTh = (float*)(ws + wBeTh); float* beG = (float*)(ws + wBeG);
  float* bePh = (float*)(ws + wBePh); float* bwe = (float*)(ws + wBwe);
  float* csw = (float*)(ws + wCsw); float* bwsum = (float*)(ws + wBwsum);
  if (b < 128){
    const int c = b, t = tid;
    {
      float s = th_bng[t] * rsqrtf(th_bnv[t] + 1e-5f);
      float d = th_bnb[t] - th_bnm[t] * s;
      float w = th_w[c*256 + t];
      ThP[c*256 + t] = (f16)(w * s);
      red[tid] = w * d; __syncthreads();
      for (int o = 128; o > 0; o >>= 1){ if (tid < o) red[tid] += red[tid+o]; __syncthreads(); }
      if (tid == 0) beTh[c] = th_b[c] + red[0];
      __syncthreads();
    }
    {
      float s = g_bng[t] * rsqrtf(g_bnv[t] + 1e-5f);
      float d = g_bnb[t] - g_bnm[t] * s;
      float w = g_w[c*256 + t];
      GP[c*256 + t] = (f16)(w * s);
      red[tid] = w * d; __syncthreads();
      for (int o = 128; o > 0; o >>= 1){ if (tid < o) red[tid] += red[tid+o]; __syncthreads(); }
      if (tid == 0) beG[c] = g_b[c] + red[0];
      __syncthreads();
    }
    {
      float s = ph_bng[t] * rsqrtf(ph_bnv[t] + 1e-5f);
      float d = ph_bnb[t] - ph_bnm[t] * s;
      float w = ph_w[c*256 + t];
      PhP[c*256 + t] = (f16)(w * s);
      red[tid] = w * d; __syncthreads();
      for (int o = 128; o > 0; o >>= 1){ if (tid < o) red[tid] += red[tid+o]; __syncthreads(); }
      if (tid == 0) bePh[c] = ph_b[c] + red[0];
    }
  } else {
    const int t = (b - 128) * 2 + (tid >> 7);
    const int c = tid & 127;
    float sW = W_bng[t] * rsqrtf(W_bnv[t] + 1e-5f);
    WP[t*128 + c] = f2bf(W_w[t*128 + c] * sW);
    if (c == 0) bwe[t] = (W_b[t] - W_bnm[t]) * sW + W_bnb[t];
    // merged prep_scalars: block b computes csw[b-128]; block 128 also computes bwsum
    {
      const int c2 = b - 128;
      float sT = W_bng[tid] * rsqrtf(W_bnv[tid] + 1e-5f);
      red[tid] = W_w[tid*128 + c2] * sT;
      __syncthreads();
      for (int o = 128; o > 0; o >>= 1){ if (tid < o) red[tid] += red[tid+o]; __syncthreads(); }
      if (tid == 0) csw[c2] = red[0];
      __syncthreads();
      if (b == 128){
        red[tid] = (W_b[tid] - W_bnm[tid]) * sT + W_bnb[tid];
        __syncthreads();
        for (int o = 128; o > 0; o >>= 1){ if (tid < o) red[tid] += red[tid+o]; __syncthreads(); }
        if (tid == 0) bwsum[0] = red[0];
      }
    }
  }
}

// =================== main kernel: 1024 blocks x 1 batch, 16 waves ===================
__global__ __launch_bounds__(NT, 1)
void stacif_main(const float* __restrict__ x1g, const float* __restrict__ x2g,
                 const char* __restrict__ ws, float* __restrict__ outg)
{
  extern __shared__ f16 sm[];
  float* Sf = (float*)(sm + SBASE);
  const int tid = threadIdx.x, bid = blockIdx.x;
  const int wid = tid >> 6, l = tid & 63;
  const float* __restrict__ x1b = x1g + (size_t)bid * BTV;
  const float* __restrict__ x2b = x2g + (size_t)bid * BTV;
  const f16* ThP = (const f16*)(ws + wThP);
  const f16* GP  = (const f16*)(ws + wGP);
  const f16* PhP = (const f16*)(ws + wPhP);
  const s16* WP  = (const s16*)(ws + wWP);
  const float* beTh = (const float*)(ws + wBeTh);
  const float* beG  = (const float*)(ws + wBeG);
  const float* bePh = (const float*)(ws + wBePh);
  const float* bwe  = (const float*)(ws + wBwe);
  const float* csw  = (const float*)(ws + wCsw);
  const float* bwsum = (const float*)(ws + wBwsum);
  s16* Up  = (s16*)(sm + UT);
  s16* USp = (s16*)(sm + US);

  // per-thread staging coords: thread (tS, qS) owns row tS, v in [qS*23, qS*23+23)
  const int tS = tid >> 2, qS = tid & 3, vB = qS * 23;

  // ---------- Ph0: two scopes (<=23 floats live): x1 load+mean+stage, then x2 load+stage ----------
  {
    float r1[23];
    const float* p1 = x1b + tS * 90;
    #pragma unroll
    for (int j = 0; j < 23; ++j){
      int off = vB + j; off = (off < 90) ? off : 89;
      r1[j] = p1[off];
    }
    float a = 0.f;
    #pragma unroll
    for (int j = 0; j < 23; ++j) if (vB + j < 90) a += r1[j];
    a += __shfl_xor(a, 1); a += __shfl_xor(a, 2);
    if (qS == 0) Sf[oX1MV + tS] = a * (1.f/90.f);
    #pragma unroll
    for (int j = 0; j < 23; ++j){
      int v = vB + j;
      if (v < 90) sm[XT + v*272 + tS] = (f16)r1[j];
    }
  }
  {
    float r2[23];
    const float* p2 = x2b + tS * 90;
    #pragma unroll
    for (int j = 0; j < 23; ++j){
      int off = vB + j; off = (off < 90) ? off : 89;
      r2[j] = p2[off];
    }
    #pragma unroll
    for (int j = 0; j < 23; ++j){
      int v = vB + j;
      if (v < 90) sm[X2 + v*272 + tS] = (f16)r2[j];
    }
  }
  __syncthreads();

  // ---------- Ph1: proj thetaT (waves 0-7, swizzled) / g1T (waves 8-15) ----------
  {
    const int mat = wid >> 3;
    const int c0 = (wid & 7) * 16;
    const f16* Wm = mat ? GP : ThP;
    const float* beg = mat ? beG : beTh;
    f32x4 acc[6] = {};
    #pragma unroll
    for (int kk = 0; kk < 8; ++kk){
      f16x8 bfr = frag_ld(Wm + c0*256 + kk*32, 256);
      #pragma unroll
      for (int vt = 0; vt < 6; ++vt){
        f16x8 a = frag_ld(sm + XT + vt*16*272 + kk*32, 272);
        acc[vt] = MFMA16(a, bfr, acc[vt]);
      }
    }
    int c = c0 + (l & 15);
    float bias = beg[c];
    #pragma unroll
    for (int vt = 0; vt < 6; ++vt){
      #pragma unroll
      for (int r = 0; r < 4; ++r){
        int v = vt*16 + (l >> 4)*4 + r;
        float val = acc[vt][r] + bias;
        if (mat) ((s16*)(sm + G1T))[v*136 + c] = (v < VV) ? f2bf(val) : (s16)0;
        else     sm[THT + v*136 + swz(v, c)] = (v < VV) ? (f16)val : (f16)0.0f;
      }
    }
  }
  __syncthreads();

  // ---------- Ph3: x2 col means + proj phiT (swizzled) / g2T; mid-barrier before overwrite ----------
  if (tid < 768){
    int v = tid >> 3, p = tid & 7;
    float a = 0.f;
    for (int j = 0; j < 32; ++j) a += (float)sm[X2 + v*272 + p*32 + j];
    a += __shfl_xor(a, 1); a += __shfl_xor(a, 2); a += __shfl_xor(a, 4);
    if (p == 0 && v < VV) Sf[oX2MT + v] = a * (1.f/256.f);
  }
  {
    const int mat = wid >> 3;
    const int c0 = (wid & 7) * 16;
    const f16* Wm = mat ? GP : PhP;
    const float* beg = mat ? beG : bePh;
    f32x4 acc[6] = {};
    #pragma unroll
    for (int kk = 0; kk < 8; ++kk){
      f16x8 bfr = frag_ld(Wm + c0*256 + kk*32, 256);
      #pragma unroll
      for (int vt = 0; vt < 6; ++vt){
        f16x8 a = frag_ld(sm + X2 + vt*16*272 + kk*32, 272);
        acc[vt] = MFMA16(a, bfr, acc[vt]);
      }
    }
    __syncthreads();   // all X2 reads complete before PHT/G2T overwrite
    int c = c0 + (l & 15);
    float bias = beg[c];
    #pragma unroll
    for (int vt = 0; vt < 6; ++vt){
      #pragma unroll
      for (int r = 0; r < 4; ++r){
        int v = vt*16 + (l >> 4)*4 + r;
        float val = acc[vt][r] + bias;
        if (mat) ((s16*)(sm + G2T))[v*136 + c] = (v < VV) ? f2bf(val) : (s16)0;
        else     sm[PHT + v*136 + swz(v, c)] = (v < VV) ? (f16)val : (f16)0.0f;
      }
    }
  }
  __syncthreads();

  // ---------- Ph45: waves 0-7: E_t + row softmax + col-partial-max; 8-13: E_s (+M_s partials) ----------
  if (wid < 8){
    int c0 = wid * 16;
    int ca = c0 + (l & 15);
    f32x4 acc[8] = {};
    for (int kk = 0; kk < 3; ++kk){
      int vb = kk*32 + (l >> 4) * 8;      // 8-aligned -> swizzle constant across bb
      int cas = swz(vb, ca);
      f16x8 a;
      #pragma unroll
      for (int bb = 0; bb < 8; ++bb) a[bb] = sm[THT + (vb + bb)*136 + cas];
      #pragma unroll
      for (int dt = 0; dt < 8; ++dt){
        int das = swz(vb, dt*16 + (l & 15));
        f16x8 bf;
        #pragma unroll
        for (int bb = 0; bb < 8; ++bb) bf[bb] = sm[PHT + (vb + bb)*136 + das];
        acc[dt] = MFMA16(a, bf, acc[dt]);
      }
    }
    #pragma unroll
    for (int dt = 0; dt < 8; ++dt){
      float m4 = fmaxf(fmaxf(acc[dt][0], acc[dt][1]), fmaxf(acc[dt][2], acc[dt][3]));
      m4 = fmaxf(m4, __shfl_xor(m4, 16));
      m4 = fmaxf(m4, __shfl_xor(m4, 32));
      if (l < 16) Up[(dt*16 + l)*136 + 128 + wid] = f2bf(m4);   // pad cols raw
    }
    #pragma unroll
    for (int r = 0; r < 4; ++r){
      float m = -3e38f;
      #pragma unroll
      for (int dt = 0; dt < 8; ++dt) m = fmaxf(m, acc[dt][r]);
      for (int sh = 1; sh < 16; sh <<= 1) m = fmaxf(m, __shfl_xor(m, sh));
      float s = 0.f;
      #pragma unroll
      for (int dt = 0; dt < 8; ++dt){ float e = __expf(acc[dt][r] - m); acc[dt][r] = e; s += e; }
      for (int sh = 1; sh < 16; sh <<= 1) s += __shfl_xor(s, sh);
      int row = c0 + (l >> 4)*4 + r;
      if ((l & 15) == 0){ Sf[oMRT + row] = m; Sf[oISRT + row] = 1.f / s; }
      #pragma unroll
      for (int dt = 0; dt < 8; ++dt) Up[row*136 + swz(row, dt*16 + (l & 15))] = f2bf(acc[dt][r]);
    }
  } else if (wid < 14){
    int v0 = (wid - 8) * 16;
    f32x4 acc[6] = {};
    for (int kk = 0; kk < 4; ++kk){
      f16x8 a = frag_ld_sw(sm + THT, 136, v0, kk*32);
      #pragma unroll
      for (int wt = 0; wt < 6; ++wt){
        f16x8 bfr = frag_ld_sw(sm + PHT, 136, wt*16, kk*32);
        acc[wt] = MFMA16(a, bfr, acc[wt]);
      }
    }
    float wmax = -3e38f;
    #pragma unroll
    for (int r = 0; r < 4; ++r){
      float m = 0.f;   // pad cols are exactly 0
      #pragma unroll
      for (int wt = 0; wt < 6; ++wt) m = fmaxf(m, acc[wt][r]);
      for (int sh = 1; sh < 16; sh <<= 1) m = fmaxf(m, __shfl_xor(m, sh));
      float s = 0.f;
      #pragma unroll
      for (int wt = 0; wt < 6; ++wt){
        float e = __expf(acc[wt][r] - m);
        bool valid = (wt*16 + (l & 15)) < VV;
        acc[wt][r] = valid ? e : 0.f;
        s += acc[wt][r];
      }
      for (int sh = 1; sh < 16; sh <<= 1) s += __shfl_xor(s, sh);
      int row = v0 + (l >> 4)*4 + r;
      if ((l & 15) == 0){ Sf[oMRS + row] = m; Sf[oISRS + row] = 1.f / s; }
      if (row < VV) wmax = fmaxf(wmax, m);
      if (row < VV){
        #pragma unroll
        for (int wt = 0; wt < 6; ++wt) USp[row*104 + wt*16 + (l & 15)] = f2bf(acc[wt][r]);
      }
    }
    wmax = fmaxf(wmax, __shfl_xor(wmax, 16));
    wmax = fmaxf(wmax, __shfl_xor(wmax, 32));
    if (l == 0) Sf[oMSP + (wid - 8)] = wmax;
  }
  __syncthreads();

  // ---------- Phase A: Et col partial sums + Es col sums + M_s ----------
  {
    int ch = wid >> 1;
    int c = (wid & 1) * 64 + l;
    bf16x8 pm8 = *(const bf16x8*)(Up + c*136 + 128);   // raw pad cols
    float mp = bf2f(pm8[0]);
    #pragma unroll
    for (int q = 1; q < 8; ++q) mp = fmaxf(mp, bf2f(pm8[q]));
    float s = 0.f;
    #pragma unroll
    for (int j = 0; j < 16; ++j){
      int d = ch*16 + j;
      float u = bf2f(Up[d*136 + swz(d, c)]);
      if (u > 0.f){
        float e1 = __expf(0.5f * (Sf[oMRT + d] - mp));
        s += (u * e1) * e1;
      }
    }
    float* PT = (float*)(sm + THT);   // THT dead; scratch
    PT[ch*128 + c] = s;
    if (ch == 0) PT[1024 + c] = mp;
  }
  if (tid < 768){
    int v = tid >> 3, p = tid & 7;
    float Ms = Sf[oMSP + 0];
    #pragma unroll
    for (int q = 1; q < 6; ++q) Ms = fmaxf(Ms, Sf[oMSP + q]);
    float s = 0.f;
    for (int j = 0; j < 12; ++j){
      int w = p*12 + j;
      if (w < VV){
        float u = bf2f(USp[w*104 + v]);
        if (u > 0.f) s += u * __expf(Sf[oMRS + w] - Ms);
      }
    }
    s += __shfl_xor(s, 1); s += __shfl_xor(s, 2); s += __shfl_xor(s, 4);
    if (p == 0) Sf[oISCS + v] = 1.f / fmaxf(s, 1e-30f);
  }
  if (tid == 0){
    float Ms = Sf[oMSP + 0];
    #pragma unroll
    for (int q = 1; q < 6; ++q) Ms = fmaxf(Ms, Sf[oMSP + q]);
    Sf[oSCAL + 8] = Ms;
  }
  __syncthreads();
  // ---------- Phase B: finalize Et col stats ----------
  if (tid < 128){
    const float* PT = (const float*)(sm + THT);
    float s = 0.f;
    #pragma unroll
    for (int q = 0; q < 8; ++q) s += PT[q*128 + tid];
    Sf[oMCT + tid] = PT[1024 + tid];
    Sf[oISCT + tid] = 1.f / s;
  }
  __syncthreads();

  // ---------- Ph7: M1 (waves 0-7), M2 (waves 8-15), stride 104 ----------
  if (wid < 8){
    int c0 = wid * 16;
    const s16* G1 = (const s16*)(sm + G1T);
    s16* M1 = (s16*)(sm + M1o);
    int ca = c0 + (l & 15);
    float mctc = Sf[oMCT + ca];
    f32x4 acc[6] = {};
    #pragma unroll
    for (int kk = 0; kk < 4; ++kk){
      int db = kk*32 + (l >> 4) * 8;    // 8-aligned -> swizzle constant across bb
      int cas = swz(db, ca);
      bf16x8 a;
      #pragma unroll
      for (int bb = 0; bb < 8; ++bb){
        float u = bf2f(Up[(db + bb)*136 + cas]);
        float val = 0.f;
        if (u > 0.f){
          float e1 = __expf(0.5f * (Sf[oMRT + db + bb] - mctc));
          val = (u * e1) * e1;
        }
        a[bb] = f2bf(val);
      }
      #pragma unroll
      for (int vt = 0; vt < 6; ++vt){
        bf16x8 bfv = bfrag_ld(G1 + vt*16*136 + kk*32, 136);
        acc[vt] = MFMABF(a, bfv, acc[vt]);
      }
    }
    #pragma unroll
    for (int vt = 0; vt < 6; ++vt){
      int v = vt*16 + (l & 15);
      float cs = (v < VV) ? Sf[oISRS + v] : 0.f;
      #pragma unroll
      for (int r = 0; r < 4; ++r){
        int c = c0 + (l >> 4)*4 + r;
        M1[c*104 + v] = f2bf(acc[vt][r] * Sf[oISCT + c] * cs);
      }
    }
  } else {
    int c0 = (wid - 8) * 16;
    const s16* G2 = (const s16*)(sm + G2T);
    s16* M2 = (s16*)(sm + M2o);
    f32x4 acc[6] = {};
    #pragma unroll
    for (int kk = 0; kk < 4; ++kk){
      bf16x8 a = bfrag_ld_sw(Up, 136, c0, kk*32);
      #pragma unroll
      for (int vt = 0; vt < 6; ++vt){
        bf16x8 bfv = bfrag_ld(G2 + vt*16*136 + kk*32, 136);
        acc[vt] = MFMABF(a, bfv, acc[vt]);
      }
    }
    #pragma unroll
    for (int vt = 0; vt < 6; ++vt){
      int v = vt*16 + (l & 15);
      float cs = (v < VV) ? Sf[oISCS + v] : 0.f;
      #pragma unroll
      for (int r = 0; r < 4; ++r){
        int c = c0 + (l >> 4)*4 + r;
        M2[c*104 + v] = f2bf(acc[vt][r] * Sf[oISRT + c] * cs);
      }
    }
  }
  __syncthreads();

  // ---------- Ph8: z1T / z2T — 48 balanced units, M/US stride 104 ----------
  for (int pass = 0; pass < 3; ++pass){
    int u = wid + pass*16;          // 0..47
    bool isZ2 = u >= 24;
    int rem = isZ2 ? u - 24 : u;    // 0..23
    int w0 = (rem >> 2) * 16;       // 6 w-tiles
    int cq = rem & 3;               // 4 col-quarters, 2 ct each
    int wa = w0 + (l & 15);
    const s16* Mx = (const s16*)(sm + (isZ2 ? M2o : M1o));
    s16* Z = (s16*)(sm + (isZ2 ? Z2o : Z1o));
    int wr = (wa < VV) ? wa : (VV - 1);
    float e_row = isZ2 ? __expf(Sf[oMRS + wr] - Sf[oSCAL + 8]) : 0.f;
    f32x4 acc[2] = {};
    #pragma unroll
    for (int kk = 0; kk < 3; ++kk){
      int vb = kk*32 + (l >> 4) * 8;
      bf16x8 a;
      if (!isZ2){
        #pragma unroll
        for (int bb = 0; bb < 8; ++bb){
          int v = vb + bb;
          a[bb] = (v < VV) ? USp[v*104 + wa] : (s16)0;
        }
      } else {
        bf16x8 uv = *(const bf16x8*)(USp + wr*104 + vb);   // contiguous row read
        #pragma unroll
        for (int bb = 0; bb < 8; ++bb){
          a[bb] = f2bf(bf2f(uv[bb]) * e_row);
        }
      }
      #pragma unroll
      for (int ct = 0; ct < 2; ++ct){
        bf16x8 bfv = bfrag_ld(Mx + (cq*2 + ct)*16*104 + kk*32, 104);
        acc[ct] = MFMABF(a, bfv, acc[ct]);
      }
    }
    #pragma unroll
    for (int ct = 0; ct < 2; ++ct){
      #pragma unroll
      for (int r = 0; r < 4; ++r){
        int row = w0 + (l >> 4)*4 + r;
        Z[row*136 + (cq*2 + ct)*16 + (l & 15)] = f2bf(acc[ct][r]);
      }
    }
  }
  __syncthreads();

  // ---------- Ph9a: z column sums ----------
  {
    int col = tid >> 3, zi = (tid >> 2) & 1, p = tid & 3;
    const s16* Z = (const s16*)(sm + (zi ? Z2o : Z1o));
    float s = 0.f;
    for (int j = 0; j < 23; ++j){
      int w = p*23 + j;
      if (w < VV) s += bf2f(Z[w*136 + col]);
    }
    s += __shfl_xor(s, 1); s += __shfl_xor(s, 2);
    if (p == 0){
      float* R = Sf + (zi ? oRED2 : oRED1);
      R[col] = csw[col] * s;
    }
  }
  __syncthreads();
  // ---------- Ph9b: wave 0 does all reductions + fusion weights ----------
  if (wid == 0){
    float s1 = Sf[oRED1 + l] + Sf[oRED1 + 64 + l];
    float s2 = Sf[oRED2 + l] + Sf[oRED2 + 64 + l];
    float t1 = Sf[oX1MV + l] + Sf[oX1MV + 64 + l] + Sf[oX1MV + 128 + l] + Sf[oX1MV + 192 + l];
    float t2 = (l < VV) ? Sf[oX2MT + l] : 0.f;
    if (l < 26) t2 += Sf[oX2MT + 64 + l];
    for (int sh = 1; sh < 64; sh <<= 1){
      s1 += __shfl_xor(s1, sh);
      s2 += __shfl_xor(s2, sh);
      t1 += __shfl_xor(t1, sh);
      t2 += __shfl_xor(t2, sh);
    }
    if (l == 0){
      float m1 = t1 * (1.f/256.f);
      float m2 = t2 * (1.f/90.f);
      float bws = bwsum[0];
      float mp1 = (s1 + 90.f*bws) * (1.f/23040.f);
      float mp2 = (s2 + 90.f*bws) * (1.f/23040.f);
      {
        float mx = fmaxf(m1, fmaxf(m2, mp1));
        float e0 = __expf(m1-mx), e1 = __expf(m2-mx), e2 = __expf(mp1-mx);
        float inv = 1.f/(e0+e1+e2);
        Sf[oSCAL+0] = e0*inv; Sf[oSCAL+1] = e1*inv; Sf[oSCAL+2] = e2*inv;
      }
      {
        float mx = fmaxf(m2, fmaxf(m1, mp2));
        float e0 = __expf(m2-mx), e1 = __expf(m1-mx), e2 = __expf(mp2-mx);
        float inv = 1.f/(e0+e1+e2);
        Sf[oSCAL+3] = e0*inv; Sf[oSCAL+4] = e1*inv; Sf[oSCAL+5] = e2*inv;
      }
    }
  }
  __syncthreads();

  // ---------- Ph10: proj + (cross,bias) -> f16 LDS staging; x-term deferred to flush ----------
  for (int pass = 0; pass < 2; ++pass){
    int u = wid + pass*16;
    bool is2 = u & 1;
    int t0 = (u >> 1) * 16;
    const s16* Zp = (const s16*)(sm + (is2 ? Z2o : Z1o));
    f32x4 acc[6] = {};
    #pragma unroll
    for (int kk = 0; kk < 4; ++kk){
      bf16x8 a = bfrag_ld(WP + t0*128 + kk*32, 128);
      #pragma unroll
      for (int vt = 0; vt < 6; ++vt){
        bf16x8 bfr = bfrag_ld(Zp + vt*16*136 + kk*32, 136);
        acc[vt] = MFMABF(a, bfr, acc[vt]);
      }
    }
    f16* OS = sm + (is2 ? OS2 : OS1);
    float wb = is2 ? Sf[oSCAL+4] : Sf[oSCAL+1];
    float wc = is2 ? Sf[oSCAL+5] : Sf[oSCAL+2];
    #pragma unroll
    for (int r = 0; r < 4; ++r){
      int t = t0 + (l >> 4)*4 + r;
      float bw = bwe[t];
      float crossv = is2 ? Sf[oX1MV + t] : 0.f;
      #pragma unroll
      for (int vt = 0; vt < 6; ++vt){
        int v = vt*16 + (l & 15);
        if (v < VV){
          float cross = is2 ? crossv : Sf[oX2MT + v];
          OS[t*90 + v] = (f16)(wb * cross + wc * (acc[vt][r] + bw));
        }
      }
    }
  }
  __syncthreads();

  // ---------- Ph11: coalesced flush with x folded in (float4 reads+stores) ----------
  {
    float* out1 = outg + (size_t)bid * BTV;
    float* out2 = outg + (size_t)NB * BTV + (size_t)bid * BTV;
    const float4* x14 = (const float4*)x1b;
    const float4* x24 = (const float4*)x2b;
    float wa1 = Sf[oSCAL+0], wa2 = Sf[oSCAL+3];
    #pragma unroll
    for (int k = 0; k < 3; ++k){
      int e = (k*1024 + tid) * 8;
      if (e < BTV){
        float4 xa = x14[e/4], xb4 = x14[e/4 + 1];
        float4 xc = x24[e/4], xd4 = x24[e/4 + 1];
        f16x8 h1 = *(const f16x8*)(sm + OS1 + e);
        f16x8 h2 = *(const f16x8*)(sm + OS2 + e);
        float4 a1 = {wa1*xa.x + (float)h1[0], wa1*xa.y + (float)h1[1],
                     wa1*xa.z + (float)h1[2], wa1*xa.w + (float)h1[3]};
        float4 b1 = {wa1*xb4.x + (float)h1[4], wa1*xb4.y + (float)h1[5],
                     wa1*xb4.z + (float)h1[6], wa1*xb4.w + (float)h1[7]};
        float4 a2 = {wa2*xc.x + (float)h2[0], wa2*xc.y + (float)h2[1],
                     wa2*xc.z + (float)h2[2], wa2*xc.w + (float)h2[3]};
        float4 b2 = {wa2*xd4.x + (float)h2[4], wa2*xd4.y + (float)h2[5],
                     wa2*xd4.z + (float)h2[6], wa2*xd4.w + (float)h2[7]};
        *(float4*)(out1 + e)     = a1;
        *(float4*)(out1 + e + 4) = b1;
        *(float4*)(out2 + e)     = a2;
        *(float4*)(out2 + e + 4) = b2;
      }
    }
  }
}

} // namespace

extern "C" void kernel_launch(void* const* d_in, const int* in_sizes, int n_in,
                              void* d_out, int out_size, void* d_ws, size_t ws_size,
                              hipStream_t stream)
{
  (void)in_sizes; (void)n_in; (void)out_size; (void)ws_size;
  hipFuncSetAttribute((const void*)stacif_main,
                      hipFuncAttributeMaxDynamicSharedMemorySize, SMEM_BYTES);

  const float* x1 = (const float*)d_in[0];
  const float* x2 = (const float*)d_in[1];
  const float* g_bng = (const float*)d_in[2];
  const float* g_bnb = (const float*)d_in[3];
  const float* g_bnm = (const float*)d_in[4];
  const float* g_bnv = (const float*)d_in[5];
  const float* g_w   = (const float*)d_in[6];
  const float* g_b   = (const float*)d_in[7];
  const float* th_bng = (const float*)d_in[8];
  const float* th_bnb = (const float*)d_in[9];
  const float* th_bnm = (const float*)d_in[10];
  const float* th_bnv = (const float*)d_in[11];
  const float* th_w   = (const float*)d_in[12];
  const float* th_b   = (const float*)d_in[13];
  const float* ph_bng = (const float*)d_in[14];
  const float* ph_bnb = (const float*)d_in[15];
  const float* ph_bnm = (const float*)d_in[16];
  const float* ph_bnv = (const float*)d_in[17];
  const float* ph_w   = (const float*)d_in[18];
  const float* ph_b   = (const float*)d_in[19];
  const float* W_w    = (const float*)d_in[20];
  const float* W_b    = (const float*)d_in[21];
  const float* W_bng  = (const float*)d_in[22];
  const float* W_bnb  = (const float*)d_in[23];
  const float* W_bnm  = (const float*)d_in[24];
  const float* W_bnv  = (const float*)d_in[25];
  char* ws = (char*)d_ws;
  float* out = (float*)d_out;

  prep_weights<<<dim3(256), dim3(256), 0, stream>>>(
      th_w, th_b, th_bng, th_bnb, th_bnm, th_bnv,
      g_w, g_b, g_bng, g_bnb, g_bnm, g_bnv,
      ph_w, ph_b, ph_bng, ph_bnb, ph_bnm, ph_bnv,
      W_w, W_b, W_bng, W_bnb, W_bnm, W_bnv, ws);
  stacif_main<<<dim3(NB), dim3(NT), SMEM_BYTES, stream>>>(x1, x2, ws, out);
}

// Round 15
// 236.656 us; speedup vs baseline: 1.2665x; 1.0169x over previous
//
#include <hip/hip_runtime.h>

typedef unsigned int u32;
typedef _Float16 f16;
typedef short s16;
typedef _Float16 f16x8 __attribute__((ext_vector_type(8)));
typedef short bf16x8 __attribute__((ext_vector_type(8)));
typedef float f32x4 __attribute__((ext_vector_type(4)));

#define MFMA16(a,b,c) __builtin_amdgcn_mfma_f32_16x16x32_f16(a,b,c,0,0,0)
#define MFMABF(a,b,c) __builtin_amdgcn_mfma_f32_16x16x32_bf16(a,b,c,0,0,0)

namespace {

constexpr int VV = 90, BTV = 256*90, NB = 1024, NT = 1024;

// ---- LDS layout (2-byte-element offsets) ----
constexpr int XT  = 0;         // f16 [96][272] x1T staging (dead after Ph1 MFMA)
constexpr int TH2 = 0;         // f16 [128][104] theta c-major (Ph1-epi -> Ph45-mid)
constexpr int PH2 = 13312;     // f16 [128][104] phi c-major (Ph3-epi -> Ph45-mid)
constexpr int UT  = 0;         // bf16 [128][136] swizzled (Ph45-mid ->); cols 128..135 raw partial-max
constexpr int OS1 = 0;         // f16 [256][90] out1 staging (Ph10)
constexpr int US  = 17408;     // bf16 [90][104]  (Ph45-mid ->, ends 26768)
constexpr int G1T = 26768;     // bf16 [96][136]  (ends 39824)
constexpr int THT = 39824;     // f16 [96][136] v-major plain; f32 scratch in Phase A
constexpr int PHT = 52880;     // f16 [96][136] v-major plain (ends 65936)
constexpr int X2  = 52880;     // f16 [96][272] x2T staging (ends 78992; dead before PHT/G2T writes)
constexpr int G2T = 66448;     // bf16 [96][136]  (ends 79504)
constexpr int M1o = 39824;     // bf16 [128][104] over THT (ends 53136)
constexpr int M2o = 53136;     // bf16 [128][104] over PHT (ends 66448)
constexpr int Z1o = 26768;     // bf16 [96][136]  over G1T
constexpr int Z2o = 66448;     // bf16 [96][136]  over G2T
constexpr int OS2 = 39824;     // f16 [256][90] out2 staging over M1/M2 (ends 62864)
constexpr int SBASE = 79504;   // f32 stats area (byte 159008)
constexpr int oX1MV=0, oX2MT=256, oMRT=352, oISRT=480, oMCT=608, oISCT=736,
              oMRS=864, oISRS=960, oISCS=1056, oSCAL=1152, oMSP=1168;
constexpr int oRED1=608, oRED2=736;   // overlay MCT/ISCT (dead after Ph7)
constexpr int SWORDS = 1184;
constexpr int SMEM_BYTES = SBASE*2 + SWORDS*4;   // 163744 <= 163840

// ---- ws layout (bytes) ----
constexpr size_t wThP=0, wGP=65536, wPhP=131072, wWP=196608,
  wBeTh=262144, wBeG=262656, wBePh=263168, wBwe=263680, wCsw=264704, wBwsum=265216;

// XOR swizzle for UT only (still column-gathered in PhaseA / Ph7-M1)
__device__ __forceinline__ int swz(int row, int col){
  return col ^ (((row >> 3) & 3) << 4);
}

__device__ __forceinline__ f16x8 frag_ld(const f16* p, int stride){
  int l = threadIdx.x & 63;
  return *(const f16x8*)(p + (l & 15) * stride + (l >> 4) * 8);
}
__device__ __forceinline__ bf16x8 bfrag_ld(const s16* p, int stride){
  int l = threadIdx.x & 63;
  return *(const bf16x8*)(p + (l & 15) * stride + (l >> 4) * 8);
}
__device__ __forceinline__ bf16x8 bfrag_ld_sw(const s16* p, int stride, int rowbase, int colbase){
  int l = threadIdx.x & 63;
  int row = rowbase + (l & 15);
  int col = (colbase + (l >> 4) * 8) ^ (((row >> 3) & 3) << 4);
  return *(const bf16x8*)(p + row * stride + col);
}
__device__ __forceinline__ s16 f2bf(float x){
  u32 u = __float_as_uint(x);
  u += 0x7FFFu + ((u >> 16) & 1u);   // RNE
  return (s16)(u >> 16);
}
__device__ __forceinline__ float bf2f(s16 h){
  return __uint_as_float(((u32)(unsigned short)h) << 16);
}

// =================== single prep kernel ===================
__global__ void prep_weights(
    const float* __restrict__ th_w, const float* __restrict__ th_b,
    const float* __restrict__ th_bng, const float* __restrict__ th_bnb,
    const float* __restrict__ th_bnm, const float* __restrict__ th_bnv,
    const float* __restrict__ g_w, const float* __restrict__ g_b,
    const float* __restrict__ g_bng, const float* __restrict__ g_bnb,
    const float* __restrict__ g_bnm, const float* __restrict__ g_bnv,
    const float* __restrict__ ph_w, const float* __restrict__ ph_b,
    const float* __restrict__ ph_bng, const float* __restrict__ ph_bnb,
    const float* __restrict__ ph_bnm, const float* __restrict__ ph_bnv,
    const float* __restrict__ W_w, const float* __restrict__ W_b,
    const float* __restrict__ W_bng, const float* __restrict__ W_bnb,
    const float* __restrict__ W_bnm, const float* __restrict__ W_bnv,
    char* __restrict__ ws)
{
  __shared__ float red[256];
  const int b = blockIdx.x, tid = threadIdx.x;
  f16* ThP = (f16*)(ws + wThP); f16* GP = (f16*)(ws + wGP);
  f16* PhP = (f16*)(ws + wPhP); s16* WP = (s16*)(ws + wWP);
  float* beTh = (float*)(ws + wBeTh); float* beG = (float*)(ws + wBeG);
  float* bePh = (float*)(ws + wBePh); float* bwe = (float*)(ws + wBwe);
  float* csw = (float*)(ws + wCsw); float* bwsum = (float*)(ws + wBwsum);
  if (b < 128){
    const int c = b, t = tid;
    {
      float s = th_bng[t] * rsqrtf(th_bnv[t] + 1e-5f);
      float d = th_bnb[t] - th_bnm[t] * s;
      float w = th_w[c*256 + t];
      ThP[c*256 + t] = (f16)(w * s);
      red[tid] = w * d; __syncthreads();
      for (int o = 128; o > 0; o >>= 1){ if (tid < o) red[tid] += red[tid+o]; __syncthreads(); }
      if (tid == 0) beTh[c] = th_b[c] + red[0];
      __syncthreads();
    }
    {
      float s = g_bng[t] * rsqrtf(g_bnv[t] + 1e-5f);
      float d = g_bnb[t] - g_bnm[t] * s;
      float w = g_w[c*256 + t];
      GP[c*256 + t] = (f16)(w * s);
      red[tid] = w * d; __syncthreads();
      for (int o = 128; o > 0; o >>= 1){ if (tid < o) red[tid] += red[tid+o]; __syncthreads(); }
      if (tid == 0) beG[c] = g_b[c] + red[0];
      __syncthreads();
    }
    {
      float s = ph_bng[t] * rsqrtf(ph_bnv[t] + 1e-5f);
      float d = ph_bnb[t] - ph_bnm[t] * s;
      float w = ph_w[c*256 + t];
      PhP[c*256 + t] = (f16)(w * s);
      red[tid] = w * d; __syncthreads();
      for (int o = 128; o > 0; o >>= 1){ if (tid < o) red[tid] += red[tid+o]; __syncthreads(); }
      if (tid == 0) bePh[c] = ph_b[c] + red[0];
    }
  } else {
    const int t = (b - 128) * 2 + (tid >> 7);
    const int c = tid & 127;
    float sW = W_bng[t] * rsqrtf(W_bnv[t] + 1e-5f);
    WP[t*128 + c] = f2bf(W_w[t*128 + c] * sW);
    if (c == 0) bwe[t] = (W_b[t] - W_bnm[t]) * sW + W_bnb[t];
    {
      const int c2 = b - 128;
      float sT = W_bng[tid] * rsqrtf(W_bnv[tid] + 1e-5f);
      red[tid] = W_w[tid*128 + c2] * sT;
      __syncthreads();
      for (int o = 128; o > 0; o >>= 1){ if (tid < o) red[tid] += red[tid+o]; __syncthreads(); }
      if (tid == 0) csw[c2] = red[0];
      __syncthreads();
      if (b == 128){
        red[tid] = (W_b[tid] - W_bnm[tid]) * sT + W_bnb[tid];
        __syncthreads();
        for (int o = 128; o > 0; o >>= 1){ if (tid < o) red[tid] += red[tid+o]; __syncthreads(); }
        if (tid == 0) bwsum[0] = red[0];
      }
    }
  }
}

// =================== main kernel: 1024 blocks x 1 batch, 16 waves ===================
__global__ __launch_bounds__(NT, 1)
void stacif_main(const float* __restrict__ x1g, const float* __restrict__ x2g,
                 const char* __restrict__ ws, float* __restrict__ outg)
{
  extern __shared__ f16 sm[];
  float* Sf = (float*)(sm + SBASE);
  const int tid = threadIdx.x, bid = blockIdx.x;
  const int wid = tid >> 6, l = tid & 63;
  const float* __restrict__ x1b = x1g + (size_t)bid * BTV;
  const float* __restrict__ x2b = x2g + (size_t)bid * BTV;
  const f16* ThP = (const f16*)(ws + wThP);
  const f16* GP  = (const f16*)(ws + wGP);
  const f16* PhP = (const f16*)(ws + wPhP);
  const s16* WP  = (const s16*)(ws + wWP);
  const float* beTh = (const float*)(ws + wBeTh);
  const float* beG  = (const float*)(ws + wBeG);
  const float* bePh = (const float*)(ws + wBePh);
  const float* bwe  = (const float*)(ws + wBwe);
  const float* csw  = (const float*)(ws + wCsw);
  const float* bwsum = (const float*)(ws + wBwsum);
  s16* Up  = (s16*)(sm + UT);
  s16* USp = (s16*)(sm + US);

  // per-thread staging coords: thread (tS, qS) owns row tS, v in [qS*23, qS*23+23)
  const int tS = tid >> 2, qS = tid & 3, vB = qS * 23;

  // ---------- Ph0: two scopes: x1 load+mean+stage, then x2 load+stage ----------
  {
    float r1[23];
    const float* p1 = x1b + tS * 90;
    #pragma unroll
    for (int j = 0; j < 23; ++j){
      int off = vB + j; off = (off < 90) ? off : 89;
      r1[j] = p1[off];
    }
    float a = 0.f;
    #pragma unroll
    for (int j = 0; j < 23; ++j) if (vB + j < 90) a += r1[j];
    a += __shfl_xor(a, 1); a += __shfl_xor(a, 2);
    if (qS == 0) Sf[oX1MV + tS] = a * (1.f/90.f);
    #pragma unroll
    for (int j = 0; j < 23; ++j){
      int v = vB + j;
      if (v < 90) sm[XT + v*272 + tS] = (f16)r1[j];
    }
  }
  {
    float r2[23];
    const float* p2 = x2b + tS * 90;
    #pragma unroll
    for (int j = 0; j < 23; ++j){
      int off = vB + j; off = (off < 90) ? off : 89;
      r2[j] = p2[off];
    }
    #pragma unroll
    for (int j = 0; j < 23; ++j){
      int v = vB + j;
      if (v < 90) sm[X2 + v*272 + tS] = (f16)r2[j];
    }
  }
  __syncthreads();

  // ---------- Ph1: proj thetaT (waves 0-7) / g1T (waves 8-15); dual-layout theta ----------
  {
    const int mat = wid >> 3;
    const int c0 = (wid & 7) * 16;
    const f16* Wm = mat ? GP : ThP;
    const float* beg = mat ? beG : beTh;
    f32x4 acc[6] = {};
    #pragma unroll
    for (int kk = 0; kk < 8; ++kk){
      f16x8 bfr = frag_ld(Wm + c0*256 + kk*32, 256);
      #pragma unroll
      for (int vt = 0; vt < 6; ++vt){
        f16x8 a = frag_ld(sm + XT + vt*16*272 + kk*32, 272);
        acc[vt] = MFMA16(a, bfr, acc[vt]);
      }
    }
    __syncthreads();   // all XT reads done before TH2 (over XT) is written
    int c = c0 + (l & 15);
    float bias = beg[c];
    #pragma unroll
    for (int vt = 0; vt < 6; ++vt){
      #pragma unroll
      for (int r = 0; r < 4; ++r){
        int v = vt*16 + (l >> 4)*4 + r;
        float val = acc[vt][r] + bias;
        if (mat){
          ((s16*)(sm + G1T))[v*136 + c] = (v < VV) ? f2bf(val) : (s16)0;
        } else {
          f16 h = (v < VV) ? (f16)val : (f16)0.0f;
          sm[THT + v*136 + c] = h;        // v-major (for E_s)
          sm[TH2 + c*104 + v] = h;        // c-major (for E_t)
        }
      }
    }
  }
  __syncthreads();

  // ---------- Ph3: x2 col means + proj phiT (dual) / g2T; mid-barrier before overwrite ----------
  if (tid < 768){
    int v = tid >> 3, p = tid & 7;
    float a = 0.f;
    for (int j = 0; j < 32; ++j) a += (float)sm[X2 + v*272 + p*32 + j];
    a += __shfl_xor(a, 1); a += __shfl_xor(a, 2); a += __shfl_xor(a, 4);
    if (p == 0 && v < VV) Sf[oX2MT + v] = a * (1.f/256.f);
  }
  {
    const int mat = wid >> 3;
    const int c0 = (wid & 7) * 16;
    const f16* Wm = mat ? GP : PhP;
    const float* beg = mat ? beG : bePh;
    f32x4 acc[6] = {};
    #pragma unroll
    for (int kk = 0; kk < 8; ++kk){
      f16x8 bfr = frag_ld(Wm + c0*256 + kk*32, 256);
      #pragma unroll
      for (int vt = 0; vt < 6; ++vt){
        f16x8 a = frag_ld(sm + X2 + vt*16*272 + kk*32, 272);
        acc[vt] = MFMA16(a, bfr, acc[vt]);
      }
    }
    __syncthreads();   // all X2 reads complete before PHT/G2T/PH2 overwrite
    int c = c0 + (l & 15);
    float bias = beg[c];
    #pragma unroll
    for (int vt = 0; vt < 6; ++vt){
      #pragma unroll
      for (int r = 0; r < 4; ++r){
        int v = vt*16 + (l >> 4)*4 + r;
        float val = acc[vt][r] + bias;
        if (mat){
          ((s16*)(sm + G2T))[v*136 + c] = (v < VV) ? f2bf(val) : (s16)0;
        } else {
          f16 h = (v < VV) ? (f16)val : (f16)0.0f;
          sm[PHT + v*136 + c] = h;        // v-major (for E_s)
          sm[PH2 + c*104 + v] = h;        // c-major (for E_t)
        }
      }
    }
  }
  __syncthreads();

  // ---------- Ph45: E_t via c-major frags (waves 0-7) | E_s (waves 8-13); mid-barrier; epilogues ----------
  {
    f32x4 acc[8] = {};
    if (wid < 8){
      int c0 = wid * 16;
      #pragma unroll
      for (int kk = 0; kk < 3; ++kk){
        f16x8 a = frag_ld(sm + TH2 + c0*104 + kk*32, 104);
        #pragma unroll
        for (int dt = 0; dt < 8; ++dt){
          f16x8 bfr = frag_ld(sm + PH2 + dt*16*104 + kk*32, 104);
          acc[dt] = MFMA16(a, bfr, acc[dt]);
        }
      }
    } else if (wid < 14){
      int v0 = (wid - 8) * 16;
      #pragma unroll
      for (int kk = 0; kk < 4; ++kk){
        f16x8 a = frag_ld(sm + THT + v0*136 + kk*32, 136);
        #pragma unroll
        for (int wt = 0; wt < 6; ++wt){
          f16x8 bfr = frag_ld(sm + PHT + wt*16*136 + kk*32, 136);
          acc[wt] = MFMA16(a, bfr, acc[wt]);
        }
      }
    }
    __syncthreads();   // TH2/PH2 dead; UT/US regions now writable
    if (wid < 8){
      int c0 = wid * 16;
      #pragma unroll
      for (int dt = 0; dt < 8; ++dt){
        float m4 = fmaxf(fmaxf(acc[dt][0], acc[dt][1]), fmaxf(acc[dt][2], acc[dt][3]));
        m4 = fmaxf(m4, __shfl_xor(m4, 16));
        m4 = fmaxf(m4, __shfl_xor(m4, 32));
        if (l < 16) Up[(dt*16 + l)*136 + 128 + wid] = f2bf(m4);   // pad cols raw
      }
      #pragma unroll
      for (int r = 0; r < 4; ++r){
        float m = -3e38f;
        #pragma unroll
        for (int dt = 0; dt < 8; ++dt) m = fmaxf(m, acc[dt][r]);
        for (int sh = 1; sh < 16; sh <<= 1) m = fmaxf(m, __shfl_xor(m, sh));
        float s = 0.f;
        #pragma unroll
        for (int dt = 0; dt < 8; ++dt){ float e = __expf(acc[dt][r] - m); acc[dt][r] = e; s += e; }
        for (int sh = 1; sh < 16; sh <<= 1) s += __shfl_xor(s, sh);
        int row = c0 + (l >> 4)*4 + r;
        if ((l & 15) == 0){ Sf[oMRT + row] = m; Sf[oISRT + row] = 1.f / s; }
        #pragma unroll
        for (int dt = 0; dt < 8; ++dt) Up[row*136 + swz(row, dt*16 + (l & 15))] = f2bf(acc[dt][r]);
      }
    } else if (wid < 14){
      int v0 = (wid - 8) * 16;
      float wmax = -3e38f;
      #pragma unroll
      for (int r = 0; r < 4; ++r){
        float m = 0.f;   // pad cols are exactly 0
        #pragma unroll
        for (int wt = 0; wt < 6; ++wt) m = fmaxf(m, acc[wt][r]);
        for (int sh = 1; sh < 16; sh <<= 1) m = fmaxf(m, __shfl_xor(m, sh));
        float s = 0.f;
        #pragma unroll
        for (int wt = 0; wt < 6; ++wt){
          float e = __expf(acc[wt][r] - m);
          bool valid = (wt*16 + (l & 15)) < VV;
          acc[wt][r] = valid ? e : 0.f;
          s += acc[wt][r];
        }
        for (int sh = 1; sh < 16; sh <<= 1) s += __shfl_xor(s, sh);
        int row = v0 + (l >> 4)*4 + r;
        if ((l & 15) == 0){ Sf[oMRS + row] = m; Sf[oISRS + row] = 1.f / s; }
        if (row < VV) wmax = fmaxf(wmax, m);
        if (row < VV){
          #pragma unroll
          for (int wt = 0; wt < 6; ++wt) USp[row*104 + wt*16 + (l & 15)] = f2bf(acc[wt][r]);
        }
      }
      wmax = fmaxf(wmax, __shfl_xor(wmax, 16));
      wmax = fmaxf(wmax, __shfl_xor(wmax, 32));
      if (l == 0) Sf[oMSP + (wid - 8)] = wmax;
    }
  }
  __syncthreads();

  // ---------- Phase A: Et col partial sums + Es col sums + M_s ----------
  {
    int ch = wid >> 1;
    int c = (wid & 1) * 64 + l;
    bf16x8 pm8 = *(const bf16x8*)(Up + c*136 + 128);   // raw pad cols
    float mp = bf2f(pm8[0]);
    #pragma unroll
    for (int q = 1; q < 8; ++q) mp = fmaxf(mp, bf2f(pm8[q]));
    float s = 0.f;
    #pragma unroll
    for (int j = 0; j < 16; ++j){
      int d = ch*16 + j;
      float u = bf2f(Up[d*136 + swz(d, c)]);
      if (u > 0.f){
        float e1 = __expf(0.5f * (Sf[oMRT + d] - mp));
        s += (u * e1) * e1;
      }
    }
    float* PT = (float*)(sm + THT);   // THT dead; scratch
    PT[ch*128 + c] = s;
    if (ch == 0) PT[1024 + c] = mp;
  }
  if (tid < 768){
    int v = tid >> 3, p = tid & 7;
    float Ms = Sf[oMSP + 0];
    #pragma unroll
    for (int q = 1; q < 6; ++q) Ms = fmaxf(Ms, Sf[oMSP + q]);
    float s = 0.f;
    for (int j = 0; j < 12; ++j){
      int w = p*12 + j;
      if (w < VV){
        float u = bf2f(USp[w*104 + v]);
        if (u > 0.f) s += u * __expf(Sf[oMRS + w] - Ms);
      }
    }
    s += __shfl_xor(s, 1); s += __shfl_xor(s, 2); s += __shfl_xor(s, 4);
    if (p == 0) Sf[oISCS + v] = 1.f / fmaxf(s, 1e-30f);
  }
  if (tid == 0){
    float Ms = Sf[oMSP + 0];
    #pragma unroll
    for (int q = 1; q < 6; ++q) Ms = fmaxf(Ms, Sf[oMSP + q]);
    Sf[oSCAL + 8] = Ms;
  }
  __syncthreads();
  // ---------- Phase B: finalize Et col stats ----------
  if (tid < 128){
    const float* PT = (const float*)(sm + THT);
    float s = 0.f;
    #pragma unroll
    for (int q = 0; q < 8; ++q) s += PT[q*128 + tid];
    Sf[oMCT + tid] = PT[1024 + tid];
    Sf[oISCT + tid] = 1.f / s;
  }
  __syncthreads();

  // ---------- Ph7: M1 (waves 0-7), M2 (waves 8-15), stride 104 ----------
  if (wid < 8){
    int c0 = wid * 16;
    const s16* G1 = (const s16*)(sm + G1T);
    s16* M1 = (s16*)(sm + M1o);
    int ca = c0 + (l & 15);
    float mctc = Sf[oMCT + ca];
    f32x4 acc[6] = {};
    #pragma unroll
    for (int kk = 0; kk < 4; ++kk){
      int db = kk*32 + (l >> 4) * 8;    // 8-aligned -> swizzle constant across bb
      int cas = swz(db, ca);
      bf16x8 a;
      #pragma unroll
      for (int bb = 0; bb < 8; ++bb){
        float u = bf2f(Up[(db + bb)*136 + cas]);
        float val = 0.f;
        if (u > 0.f){
          float e1 = __expf(0.5f * (Sf[oMRT + db + bb] - mctc));
          val = (u * e1) * e1;
        }
        a[bb] = f2bf(val);
      }
      #pragma unroll
      for (int vt = 0; vt < 6; ++vt){
        bf16x8 bfv = bfrag_ld(G1 + vt*16*136 + kk*32, 136);
        acc[vt] = MFMABF(a, bfv, acc[vt]);
      }
    }
    #pragma unroll
    for (int vt = 0; vt < 6; ++vt){
      int v = vt*16 + (l & 15);
      float cs = (v < VV) ? Sf[oISRS + v] : 0.f;
      #pragma unroll
      for (int r = 0; r < 4; ++r){
        int c = c0 + (l >> 4)*4 + r;
        M1[c*104 + v] = f2bf(acc[vt][r] * Sf[oISCT + c] * cs);
      }
    }
  } else {
    int c0 = (wid - 8) * 16;
    const s16* G2 = (const s16*)(sm + G2T);
    s16* M2 = (s16*)(sm + M2o);
    f32x4 acc[6] = {};
    #pragma unroll
    for (int kk = 0; kk < 4; ++kk){
      bf16x8 a = bfrag_ld_sw(Up, 136, c0, kk*32);
      #pragma unroll
      for (int vt = 0; vt < 6; ++vt){
        bf16x8 bfv = bfrag_ld(G2 + vt*16*136 + kk*32, 136);
        acc[vt] = MFMABF(a, bfv, acc[vt]);
      }
    }
    #pragma unroll
    for (int vt = 0; vt < 6; ++vt){
      int v = vt*16 + (l & 15);
      float cs = (v < VV) ? Sf[oISCS + v] : 0.f;
      #pragma unroll
      for (int r = 0; r < 4; ++r){
        int c = c0 + (l >> 4)*4 + r;
        M2[c*104 + v] = f2bf(acc[vt][r] * Sf[oISRT + c] * cs);
      }
    }
  }
  __syncthreads();

  // ---------- Ph8: z1T / z2T — 48 balanced units, M/US stride 104 ----------
  for (int pass = 0; pass < 3; ++pass){
    int u = wid + pass*16;          // 0..47
    bool isZ2 = u >= 24;
    int rem = isZ2 ? u - 24 : u;    // 0..23
    int w0 = (rem >> 2) * 16;       // 6 w-tiles
    int cq = rem & 3;               // 4 col-quarters, 2 ct each
    int wa = w0 + (l & 15);
    const s16* Mx = (const s16*)(sm + (isZ2 ? M2o : M1o));
    s16* Z = (s16*)(sm + (isZ2 ? Z2o : Z1o));
    int wr = (wa < VV) ? wa : (VV - 1);
    float e_row = isZ2 ? __expf(Sf[oMRS + wr] - Sf[oSCAL + 8]) : 0.f;
    f32x4 acc[2] = {};
    #pragma unroll
    for (int kk = 0; kk < 3; ++kk){
      int vb = kk*32 + (l >> 4) * 8;
      bf16x8 a;
      if (!isZ2){
        #pragma unroll
        for (int bb = 0; bb < 8; ++bb){
          int v = vb + bb;
          a[bb] = (v < VV) ? USp[v*104 + wa] : (s16)0;
        }
      } else {
        bf16x8 uv = *(const bf16x8*)(USp + wr*104 + vb);   // contiguous row read
        #pragma unroll
        for (int bb = 0; bb < 8; ++bb){
          a[bb] = f2bf(bf2f(uv[bb]) * e_row);
        }
      }
      #pragma unroll
      for (int ct = 0; ct < 2; ++ct){
        bf16x8 bfv = bfrag_ld(Mx + (cq*2 + ct)*16*104 + kk*32, 104);
        acc[ct] = MFMABF(a, bfv, acc[ct]);
      }
    }
    #pragma unroll
    for (int ct = 0; ct < 2; ++ct){
      #pragma unroll
      for (int r = 0; r < 4; ++r){
        int row = w0 + (l >> 4)*4 + r;
        Z[row*136 + (cq*2 + ct)*16 + (l & 15)] = f2bf(acc[ct][r]);
      }
    }
  }
  __syncthreads();

  // ---------- Ph9a: z column sums ----------
  {
    int col = tid >> 3, zi = (tid >> 2) & 1, p = tid & 3;
    const s16* Z = (const s16*)(sm + (zi ? Z2o : Z1o));
    float s = 0.f;
    for (int j = 0; j < 23; ++j){
      int w = p*23 + j;
      if (w < VV) s += bf2f(Z[w*136 + col]);
    }
    s += __shfl_xor(s, 1); s += __shfl_xor(s, 2);
    if (p == 0){
      float* R = Sf + (zi ? oRED2 : oRED1);
      R[col] = csw[col] * s;
    }
  }
  __syncthreads();
  // ---------- Ph9b: wave 0 does all reductions + fusion weights ----------
  if (wid == 0){
    float s1 = Sf[oRED1 + l] + Sf[oRED1 + 64 + l];
    float s2 = Sf[oRED2 + l] + Sf[oRED2 + 64 + l];
    float t1 = Sf[oX1MV + l] + Sf[oX1MV + 64 + l] + Sf[oX1MV + 128 + l] + Sf[oX1MV + 192 + l];
    float t2 = (l < VV) ? Sf[oX2MT + l] : 0.f;
    if (l < 26) t2 += Sf[oX2MT + 64 + l];
    for (int sh = 1; sh < 64; sh <<= 1){
      s1 += __shfl_xor(s1, sh);
      s2 += __shfl_xor(s2, sh);
      t1 += __shfl_xor(t1, sh);
      t2 += __shfl_xor(t2, sh);
    }
    if (l == 0){
      float m1 = t1 * (1.f/256.f);
      float m2 = t2 * (1.f/90.f);
      float bws = bwsum[0];
      float mp1 = (s1 + 90.f*bws) * (1.f/23040.f);
      float mp2 = (s2 + 90.f*bws) * (1.f/23040.f);
      {
        float mx = fmaxf(m1, fmaxf(m2, mp1));
        float e0 = __expf(m1-mx), e1 = __expf(m2-mx), e2 = __expf(mp1-mx);
        float inv = 1.f/(e0+e1+e2);
        Sf[oSCAL+0] = e0*inv; Sf[oSCAL+1] = e1*inv; Sf[oSCAL+2] = e2*inv;
      }
      {
        float mx = fmaxf(m2, fmaxf(m1, mp2));
        float e0 = __expf(m2-mx), e1 = __expf(m1-mx), e2 = __expf(mp2-mx);
        float inv = 1.f/(e0+e1+e2);
        Sf[oSCAL+3] = e0*inv; Sf[oSCAL+4] = e1*inv; Sf[oSCAL+5] = e2*inv;
      }
    }
  }
  __syncthreads();

  // ---------- Ph10: proj + (cross,bias) -> f16 LDS staging; x-term deferred to flush ----------
  for (int pass = 0; pass < 2; ++pass){
    int u = wid + pass*16;
    bool is2 = u & 1;
    int t0 = (u >> 1) * 16;
    const s16* Zp = (const s16*)(sm + (is2 ? Z2o : Z1o));
    f32x4 acc[6] = {};
    #pragma unroll
    for (int kk = 0; kk < 4; ++kk){
      bf16x8 a = bfrag_ld(WP + t0*128 + kk*32, 128);
      #pragma unroll
      for (int vt = 0; vt < 6; ++vt){
        bf16x8 bfr = bfrag_ld(Zp + vt*16*136 + kk*32, 136);
        acc[vt] = MFMABF(a, bfr, acc[vt]);
      }
    }
    f16* OS = sm + (is2 ? OS2 : OS1);
    float wb = is2 ? Sf[oSCAL+4] : Sf[oSCAL+1];
    float wc = is2 ? Sf[oSCAL+5] : Sf[oSCAL+2];
    #pragma unroll
    for (int r = 0; r < 4; ++r){
      int t = t0 + (l >> 4)*4 + r;
      float bw = bwe[t];
      float crossv = is2 ? Sf[oX1MV + t] : 0.f;
      #pragma unroll
      for (int vt = 0; vt < 6; ++vt){
        int v = vt*16 + (l & 15);
        if (v < VV){
          float cross = is2 ? crossv : Sf[oX2MT + v];
          OS[t*90 + v] = (f16)(wb * cross + wc * (acc[vt][r] + bw));
        }
      }
    }
  }
  __syncthreads();

  // ---------- Ph11: coalesced flush with x folded in ----------
  {
    float* out1 = outg + (size_t)bid * BTV;
    float* out2 = outg + (size_t)NB * BTV + (size_t)bid * BTV;
    const float4* x14 = (const float4*)x1b;
    const float4* x24 = (const float4*)x2b;
    float wa1 = Sf[oSCAL+0], wa2 = Sf[oSCAL+3];
    #pragma unroll
    for (int k = 0; k < 3; ++k){
      int e = (k*1024 + tid) * 8;
      if (e < BTV){
        float4 xa = x14[e/4], xb4 = x14[e/4 + 1];
        float4 xc = x24[e/4], xd4 = x24[e/4 + 1];
        f16x8 h1 = *(const f16x8*)(sm + OS1 + e);
        f16x8 h2 = *(const f16x8*)(sm + OS2 + e);
        float4 a1 = {wa1*xa.x + (float)h1[0], wa1*xa.y + (float)h1[1],
                     wa1*xa.z + (float)h1[2], wa1*xa.w + (float)h1[3]};
        float4 b1 = {wa1*xb4.x + (float)h1[4], wa1*xb4.y + (float)h1[5],
                     wa1*xb4.z + (float)h1[6], wa1*xb4.w + (float)h1[7]};
        float4 a2 = {wa2*xc.x + (float)h2[0], wa2*xc.y + (float)h2[1],
                     wa2*xc.z + (float)h2[2], wa2*xc.w + (float)h2[3]};
        float4 b2 = {wa2*xd4.x + (float)h2[4], wa2*xd4.y + (float)h2[5],
                     wa2*xd4.z + (float)h2[6], wa2*xd4.w + (float)h2[7]};
        *(float4*)(out1 + e)     = a1;
        *(float4*)(out1 + e + 4) = b1;
        *(float4*)(out2 + e)     = a2;
        *(float4*)(out2 + e + 4) = b2;
      }
    }
  }
}

} // namespace

extern "C" void kernel_launch(void* const* d_in, const int* in_sizes, int n_in,
                              void* d_out, int out_size, void* d_ws, size_t ws_size,
                              hipStream_t stream)
{
  (void)in_sizes; (void)n_in; (void)out_size; (void)ws_size;
  hipFuncSetAttribute((const void*)stacif_main,
                      hipFuncAttributeMaxDynamicSharedMemorySize, SMEM_BYTES);

  const float* x1 = (const float*)d_in[0];
  const float* x2 = (const float*)d_in[1];
  const float* g_bng = (const float*)d_in[2];
  const float* g_bnb = (const float*)d_in[3];
  const float* g_bnm = (const float*)d_in[4];
  const float* g_bnv = (const float*)d_in[5];
  const float* g_w   = (const float*)d_in[6];
  const float* g_b   = (const float*)d_in[7];
  const float* th_bng = (const float*)d_in[8];
  const float* th_bnb = (const float*)d_in[9];
  const float* th_bnm = (const float*)d_in[10];
  const float* th_bnv = (const float*)d_in[11];
  const float* th_w   = (const float*)d_in[12];
  const float* th_b   = (const float*)d_in[13];
  const float* ph_bng = (const float*)d_in[14];
  const float* ph_bnb = (const float*)d_in[15];
  const float* ph_bnm = (const float*)d_in[16];
  const float* ph_bnv = (const float*)d_in[17];
  const float* ph_w   = (const float*)d_in[18];
  const float* ph_b   = (const float*)d_in[19];
  const float* W_w    = (const float*)d_in[20];
  const float* W_b    = (const float*)d_in[21];
  const float* W_bng  = (const float*)d_in[22];
  const float* W_bnb  = (const float*)d_in[23];
  const float* W_bnm  = (const float*)d_in[24];
  const float* W_bnv  = (const float*)d_in[25];
  char* ws = (char*)d_ws;
  float* out = (float*)d_out;

  prep_weights<<<dim3(256), dim3(256), 0, stream>>>(
      th_w, th_b, th_bng, th_bnb, th_bnm, th_bnv,
      g_w, g_b, g_bng, g_bnb, g_bnm, g_bnv,
      ph_w, ph_b, ph_bng, ph_bnb, ph_bnm, ph_bnv,
      W_w, W_b, W_bng, W_bnb, W_bnm, W_bnv, ws);
  stacif_main<<<dim3(NB), dim3(NT), SMEM_BYTES, stream>>>(x1, x2, ws, out);
}